// Round 1
// baseline (1327.762 us; speedup 1.0000x reference)
//
#include <hip/hip_runtime.h>
#include <float.h>

#define NB      65536
#define IN_DIM  512
#define HID     256
#define LAT     64
#define NLAYERS 3
#define NK      2048

// ---------------------------------------------------------------------------
// Generic fp32 GEMM: C[M,N] = act(A[M,K] @ W[K,N] + bias), row-major.
// BM=128, BN=64, BK=32, 256 threads, per-thread tile 8x4.
// ---------------------------------------------------------------------------
template<bool RELU>
__global__ __launch_bounds__(256) void gemm_f32(
    const float* __restrict__ A, const float* __restrict__ W,
    const float* __restrict__ bias, float* __restrict__ C,
    int M, int N, int K) {
  __shared__ float As[32][132];   // [k][m], padded stride
  __shared__ float Bs[32][64];    // [k][n]
  const int tid = threadIdx.x;
  const int cg  = tid & 15;       // col group: cols cg*4 .. +3
  const int rg  = tid >> 4;       // row group: rows rg*8 .. +7
  const int m0  = blockIdx.x * 128;
  const int n0  = blockIdx.y * 64;

  float acc[8][4];
#pragma unroll
  for (int i = 0; i < 8; ++i)
#pragma unroll
    for (int j = 0; j < 4; ++j) acc[i][j] = 0.f;

  for (int k0 = 0; k0 < K; k0 += 32) {
    // stage A tile (128 rows x 32 k), transposed into As[k][m]
#pragma unroll
    for (int p = 0; p < 4; ++p) {
      int a = tid + p * 256;
      int row = a >> 3, kq = (a & 7) * 4;
      float4 v = *reinterpret_cast<const float4*>(&A[(size_t)(m0 + row) * K + k0 + kq]);
      As[kq + 0][row] = v.x; As[kq + 1][row] = v.y;
      As[kq + 2][row] = v.z; As[kq + 3][row] = v.w;
    }
    // stage B tile (32 k x 64 n)
#pragma unroll
    for (int p = 0; p < 2; ++p) {
      int a = tid + p * 256;
      int kk = a >> 4, nq = (a & 15) * 4;
      *reinterpret_cast<float4*>(&Bs[kk][nq]) =
          *reinterpret_cast<const float4*>(&W[(size_t)(k0 + kk) * N + n0 + nq]);
    }
    __syncthreads();
#pragma unroll
    for (int kk = 0; kk < 32; ++kk) {
      float4 a0 = *reinterpret_cast<const float4*>(&As[kk][rg * 8]);
      float4 a1 = *reinterpret_cast<const float4*>(&As[kk][rg * 8 + 4]);
      float4 b0 = *reinterpret_cast<const float4*>(&Bs[kk][cg * 4]);
      float av[8] = {a0.x, a0.y, a0.z, a0.w, a1.x, a1.y, a1.z, a1.w};
      float bv[4] = {b0.x, b0.y, b0.z, b0.w};
#pragma unroll
      for (int i = 0; i < 8; ++i)
#pragma unroll
        for (int j = 0; j < 4; ++j)
          acc[i][j] = fmaf(av[i], bv[j], acc[i][j]);
    }
    __syncthreads();
  }

  float4 bb = *reinterpret_cast<const float4*>(&bias[n0 + cg * 4]);
  float bv[4] = {bb.x, bb.y, bb.z, bb.w};
#pragma unroll
  for (int i = 0; i < 8; ++i) {
    float vals[4];
#pragma unroll
    for (int j = 0; j < 4; ++j) {
      float v = __fadd_rn(acc[i][j], bv[j]);
      if (RELU) v = fmaxf(v, 0.f);
      vals[j] = v;
    }
    float4 o; o.x = vals[0]; o.y = vals[1]; o.z = vals[2]; o.w = vals[3];
    *reinterpret_cast<float4*>(&C[(size_t)(m0 + rg * 8 + i) * N + n0 + cg * 4]) = o;
  }
}

// ---------------------------------------------------------------------------
// cnorm[l][k] = sum_d C[l][k][d]^2, replicating numpy's pairwise 8-acc order.
// ---------------------------------------------------------------------------
__global__ void cnorm_f32(const float* __restrict__ cb, float* __restrict__ cn) {
  int i = blockIdx.x * blockDim.x + threadIdx.x;
  if (i >= NLAYERS * NK) return;
  const float* row = cb + (size_t)i * LAT;
  float r[8];
#pragma unroll
  for (int j = 0; j < 8; ++j) r[j] = 0.f;
#pragma unroll
  for (int t = 0; t < 8; ++t)
#pragma unroll
    for (int j = 0; j < 8; ++j) {
      float v = row[t * 8 + j];
      r[j] = __fadd_rn(r[j], __fmul_rn(v, v));
    }
  cn[i] = __fadd_rn(__fadd_rn(__fadd_rn(r[0], r[1]), __fadd_rn(r[2], r[3])),
                    __fadd_rn(__fadd_rn(r[4], r[5]), __fadd_rn(r[6], r[7])));
}

// ---------------------------------------------------------------------------
// Residual quantization, all 3 layers fused (per-row sequential only).
// Block = 128 rows, 256 threads. cg=tid&15 (4 codes), rg=tid>>4 (8 rows).
// residual tile transposed in LDS; codebook chunk (64 codes) double-buffered,
// transposed + quad-swizzled; quantized kept in registers (owner quads).
// ---------------------------------------------------------------------------
__global__ __launch_bounds__(256) void rq_f32(
    const float* __restrict__ zg,     // [B][64]  (== residuals layer-0 region)
    const float* __restrict__ cb,     // [3][2048][64]
    const float* __restrict__ cnorm,  // [3][2048]
    float* __restrict__ out_codes,    // [3][B] as float
    float* __restrict__ out_quant,    // [B][64]
    float* __restrict__ out_res) {    // [3][B][64]
  __shared__ float rT[LAT][132];      // [lat][row], 128 rows + pad
  __shared__ float cbT[2][LAT][68];   // [lat][code], 64 codes + pad, swizzled
  __shared__ float cnS[2][64];
  __shared__ float rnS[128];
  __shared__ int   selS[128];

  const int tid  = threadIdx.x;
  const int cg   = tid & 15;
  const int rg   = tid >> 4;
  const int row0 = blockIdx.x * 128;

  float4 q[8];   // running quantized; owner quads: row = rg+16p, quad = cg

#pragma unroll 1
  for (int layer = 0; layer < NLAYERS; ++layer) {
    // ---- residual = z - quantized (np order); write rT + out_res ----
#pragma unroll
    for (int p = 0; p < 8; ++p) {
      int row = rg + 16 * p;
      float4 z4 = *reinterpret_cast<const float4*>(
          &zg[(size_t)(row0 + row) * LAT + cg * 4]);
      float4 r4;
      if (layer == 0) {
        r4 = z4;
      } else {
        r4.x = __fsub_rn(z4.x, q[p].x);
        r4.y = __fsub_rn(z4.y, q[p].y);
        r4.z = __fsub_rn(z4.z, q[p].z);
        r4.w = __fsub_rn(z4.w, q[p].w);
      }
      rT[cg * 4 + 0][row] = r4.x;
      rT[cg * 4 + 1][row] = r4.y;
      rT[cg * 4 + 2][row] = r4.z;
      rT[cg * 4 + 3][row] = r4.w;
      *reinterpret_cast<float4*>(
          &out_res[((size_t)layer * NB + row0 + row) * LAT + cg * 4]) = r4;
    }
    __syncthreads();

    // ---- rnorm per row (numpy pairwise 8-acc) ----
    if (tid < 128) {
      int row = tid;
      float r8[8];
#pragma unroll
      for (int j = 0; j < 8; ++j) r8[j] = 0.f;
#pragma unroll
      for (int t = 0; t < 8; ++t)
#pragma unroll
        for (int j = 0; j < 8; ++j) {
          float v = rT[t * 8 + j][row];
          r8[j] = __fadd_rn(r8[j], __fmul_rn(v, v));
        }
      rnS[row] = __fadd_rn(
          __fadd_rn(__fadd_rn(r8[0], r8[1]), __fadd_rn(r8[2], r8[3])),
          __fadd_rn(__fadd_rn(r8[4], r8[5]), __fadd_rn(r8[6], r8[7])));
    }
    // ---- stage chunk 0 into buffer 0 ----
    {
      const float* src = cb + ((size_t)layer * NK) * LAT;
#pragma unroll
      for (int p = 0; p < 4; ++p) {
        int a = tid + 256 * p;
        int code = a >> 4, s = a & 15;
        float4 v = *reinterpret_cast<const float4*>(&src[(size_t)code * LAT + s * 4]);
        int col = ((((code >> 2) + s) & 15) << 2) + (code & 3);
        cbT[0][4 * s + 0][col] = v.x;
        cbT[0][4 * s + 1][col] = v.y;
        cbT[0][4 * s + 2][col] = v.z;
        cbT[0][4 * s + 3][col] = v.w;
      }
      if (tid < 16) {
        float4 v = *reinterpret_cast<const float4*>(&cnorm[(size_t)layer * NK + tid * 4]);
        *reinterpret_cast<float4*>(&cnS[0][tid * 4]) = v;
      }
    }
    __syncthreads();

    float minv[8];
    int   mini[8];
#pragma unroll
    for (int i = 0; i < 8; ++i) { minv[i] = FLT_MAX; mini[i] = 0; }

#pragma unroll 1
    for (int ch = 0; ch < NK / 64; ++ch) {
      const int buf = ch & 1;
      // T14: issue next-chunk global loads early
      float4 nv[4]; float4 ncn;
      const bool haveNext = (ch + 1) < NK / 64;
      if (haveNext) {
        const float* src = cb + ((size_t)layer * NK + (size_t)(ch + 1) * 64) * LAT;
#pragma unroll
        for (int p = 0; p < 4; ++p) {
          int a = tid + 256 * p;
          int code = a >> 4, s = a & 15;
          nv[p] = *reinterpret_cast<const float4*>(&src[(size_t)code * LAT + s * 4]);
        }
        if (tid < 16)
          ncn = *reinterpret_cast<const float4*>(
              &cnorm[(size_t)layer * NK + (size_t)(ch + 1) * 64 + tid * 4]);
      }

      // ---- dots: 8 rows x 4 codes over 64 lat ----
      float dot[8][4];
#pragma unroll
      for (int i = 0; i < 8; ++i)
#pragma unroll
        for (int j = 0; j < 4; ++j) dot[i][j] = 0.f;

#pragma unroll 2
      for (int s = 0; s < 16; ++s) {
        int colq = (((cg + s) & 15) << 2);
#pragma unroll
        for (int jj = 0; jj < 4; ++jj) {
          int lat = 4 * s + jj;
          float4 cv = *reinterpret_cast<const float4*>(&cbT[buf][lat][colq]);
          float4 r0 = *reinterpret_cast<const float4*>(&rT[lat][rg * 8]);
          float4 r1 = *reinterpret_cast<const float4*>(&rT[lat][rg * 8 + 4]);
          float rv[8]  = {r0.x, r0.y, r0.z, r0.w, r1.x, r1.y, r1.z, r1.w};
          float cvv[4] = {cv.x, cv.y, cv.z, cv.w};
#pragma unroll
          for (int i = 0; i < 8; ++i)
#pragma unroll
            for (int j = 0; j < 4; ++j)
              dot[i][j] = fmaf(rv[i], cvv[j], dot[i][j]);
        }
      }

      // ---- distances + running argmin (np formula & rounding) ----
#pragma unroll
      for (int i = 0; i < 8; ++i) {
        float rn = rnS[rg * 8 + i];
#pragma unroll
        for (int j = 0; j < 4; ++j) {
          float d = __fadd_rn(__fsub_rn(rn, __fmul_rn(2.0f, dot[i][j])),
                              cnS[buf][cg * 4 + j]);
          int k = ch * 64 + cg * 4 + j;
          if (d < minv[i]) { minv[i] = d; mini[i] = k; }
        }
      }

      // write staged next chunk (late), then barrier
      if (haveNext) {
#pragma unroll
        for (int p = 0; p < 4; ++p) {
          int a = tid + 256 * p;
          int code = a >> 4, s = a & 15;
          int col = ((((code >> 2) + s) & 15) << 2) + (code & 3);
          cbT[buf ^ 1][4 * s + 0][col] = nv[p].x;
          cbT[buf ^ 1][4 * s + 1][col] = nv[p].y;
          cbT[buf ^ 1][4 * s + 2][col] = nv[p].z;
          cbT[buf ^ 1][4 * s + 3][col] = nv[p].w;
        }
        if (tid < 16)
          *reinterpret_cast<float4*>(&cnS[buf ^ 1][tid * 4]) = ncn;
      }
      __syncthreads();
    }

    // ---- reduce argmin across the 16 cg-threads (first-index tie-break) ----
#pragma unroll
    for (int i = 0; i < 8; ++i) {
      float v = minv[i]; int idx = mini[i];
#pragma unroll
      for (int m = 8; m >= 1; m >>= 1) {
        float ov = __shfl_xor(v, m, 64);
        int   oi = __shfl_xor(idx, m, 64);
        if (ov < v || (ov == v && oi < idx)) { v = ov; idx = oi; }
      }
      if (cg == 0) {
        int row = rg * 8 + i;
        selS[row] = idx;
        out_codes[(size_t)layer * NB + row0 + row] = (float)idx;
      }
    }
    __syncthreads();

    // ---- quantized = C[code] + quantized (np order), in registers ----
#pragma unroll
    for (int p = 0; p < 8; ++p) {
      int row = rg + 16 * p;
      int code = selS[row];
      float4 cv = *reinterpret_cast<const float4*>(
          &cb[((size_t)layer * NK + code) * LAT + cg * 4]);
      if (layer == 0) {
        q[p] = cv;
      } else {
        q[p].x = __fadd_rn(cv.x, q[p].x);
        q[p].y = __fadd_rn(cv.y, q[p].y);
        q[p].z = __fadd_rn(cv.z, q[p].z);
        q[p].w = __fadd_rn(cv.w, q[p].w);
      }
    }
    __syncthreads();
  }

  // ---- write quantized ----
#pragma unroll
  for (int p = 0; p < 8; ++p) {
    int row = rg + 16 * p;
    *reinterpret_cast<float4*>(
        &out_quant[(size_t)(row0 + row) * LAT + cg * 4]) = q[p];
  }
}

// ---------------------------------------------------------------------------
extern "C" void kernel_launch(void* const* d_in, const int* in_sizes, int n_in,
                              void* d_out, int out_size, void* d_ws, size_t ws_size,
                              hipStream_t stream) {
  (void)in_sizes; (void)n_in; (void)out_size; (void)ws_size;
  const float* x   = (const float*)d_in[0];
  const float* ew1 = (const float*)d_in[1];
  const float* eb1 = (const float*)d_in[2];
  const float* ew2 = (const float*)d_in[3];
  const float* eb2 = (const float*)d_in[4];
  const float* cbk = (const float*)d_in[5];
  const float* dw1 = (const float*)d_in[6];
  const float* db1 = (const float*)d_in[7];
  const float* dw2 = (const float*)d_in[8];
  const float* db2 = (const float*)d_in[9];

  float* out     = (float*)d_out;
  float* o_codes = out;                                   // 3*B
  float* o_xrec  = out + (size_t)NLAYERS * NB;            // B*512
  float* o_quant = o_xrec + (size_t)NB * IN_DIM;          // B*64
  float* o_res   = o_quant + (size_t)NB * LAT;            // 3*B*64

  float* h  = (float*)d_ws;                               // B*256 fp32
  float* cn = h + (size_t)NB * HID;                       // 3*2048 fp32

  // codebook norms (numpy pairwise order)
  cnorm_f32<<<(NLAYERS * NK + 255) / 256, 256, 0, stream>>>(cbk, cn);
  // encoder
  gemm_f32<true ><<<dim3(NB / 128, HID / 64),    256, 0, stream>>>(x, ew1, eb1, h,      NB, HID,    IN_DIM);
  gemm_f32<false><<<dim3(NB / 128, LAT / 64),    256, 0, stream>>>(h, ew2, eb2, o_res,  NB, LAT,    HID);
  // residual quantization (z lives in residuals[0] region)
  rq_f32<<<NB / 128, 256, 0, stream>>>(o_res, cbk, cn, o_codes, o_quant, o_res);
  // decoder
  gemm_f32<true ><<<dim3(NB / 128, HID / 64),    256, 0, stream>>>(o_quant, dw1, db1, h,      NB, HID,    LAT);
  gemm_f32<false><<<dim3(NB / 128, IN_DIM / 64), 256, 0, stream>>>(h,       dw2, db2, o_xrec, NB, IN_DIM, HID);
}

// Round 2
// 1296.988 us; speedup vs baseline: 1.0237x; 1.0237x over previous
//
#include <hip/hip_runtime.h>
#include <float.h>

#define NB      65536
#define IN_DIM  512
#define HID     256
#define LAT     64
#define NLAYERS 3
#define NK      2048

// ---------------------------------------------------------------------------
// Old-style GEMM kept for enc2 (N=64): BM=128, BN=64, BK=32, TM=8, TN=4.
// ---------------------------------------------------------------------------
template<bool RELU>
__global__ __launch_bounds__(256) void gemm_f32(
    const float* __restrict__ A, const float* __restrict__ W,
    const float* __restrict__ bias, float* __restrict__ C,
    int M, int N, int K) {
  __shared__ float As[32][132];
  __shared__ float Bs[32][64];
  const int tid = threadIdx.x;
  const int cg  = tid & 15;
  const int rg  = tid >> 4;
  const int m0  = blockIdx.x * 128;
  const int n0  = blockIdx.y * 64;

  float acc[8][4];
#pragma unroll
  for (int i = 0; i < 8; ++i)
#pragma unroll
    for (int j = 0; j < 4; ++j) acc[i][j] = 0.f;

  for (int k0 = 0; k0 < K; k0 += 32) {
#pragma unroll
    for (int p = 0; p < 4; ++p) {
      int a = tid + p * 256;
      int row = a >> 3, kq = (a & 7) * 4;
      float4 v = *reinterpret_cast<const float4*>(&A[(size_t)(m0 + row) * K + k0 + kq]);
      As[kq + 0][row] = v.x; As[kq + 1][row] = v.y;
      As[kq + 2][row] = v.z; As[kq + 3][row] = v.w;
    }
#pragma unroll
    for (int p = 0; p < 2; ++p) {
      int a = tid + p * 256;
      int kk = a >> 4, nq = (a & 15) * 4;
      *reinterpret_cast<float4*>(&Bs[kk][nq]) =
          *reinterpret_cast<const float4*>(&W[(size_t)(k0 + kk) * N + n0 + nq]);
    }
    __syncthreads();
#pragma unroll
    for (int kk = 0; kk < 32; ++kk) {
      float4 a0 = *reinterpret_cast<const float4*>(&As[kk][rg * 8]);
      float4 a1 = *reinterpret_cast<const float4*>(&As[kk][rg * 8 + 4]);
      float4 b0 = *reinterpret_cast<const float4*>(&Bs[kk][cg * 4]);
      float av[8] = {a0.x, a0.y, a0.z, a0.w, a1.x, a1.y, a1.z, a1.w};
      float bv[4] = {b0.x, b0.y, b0.z, b0.w};
#pragma unroll
      for (int i = 0; i < 8; ++i)
#pragma unroll
        for (int j = 0; j < 4; ++j)
          acc[i][j] = fmaf(av[i], bv[j], acc[i][j]);
    }
    __syncthreads();
  }

  float4 bb = *reinterpret_cast<const float4*>(&bias[n0 + cg * 4]);
  float bv[4] = {bb.x, bb.y, bb.z, bb.w};
#pragma unroll
  for (int i = 0; i < 8; ++i) {
    float vals[4];
#pragma unroll
    for (int j = 0; j < 4; ++j) {
      float v = __fadd_rn(acc[i][j], bv[j]);
      if (RELU) v = fmaxf(v, 0.f);
      vals[j] = v;
    }
    float4 o; o.x = vals[0]; o.y = vals[1]; o.z = vals[2]; o.w = vals[3];
    *reinterpret_cast<float4*>(&C[(size_t)(m0 + rg * 8 + i) * N + n0 + cg * 4]) = o;
  }
}

// ---------------------------------------------------------------------------
// Big GEMM: BM=128, BN=128, BK=16, TM=8, TN=8 (4 ds_read_b128 per 64 fma).
// k ascending sequential per thread -> bit-identical to the BK=32 version.
// ---------------------------------------------------------------------------
template<bool RELU>
__global__ __launch_bounds__(256) void gemm128(
    const float* __restrict__ A, const float* __restrict__ W,
    const float* __restrict__ bias, float* __restrict__ C,
    int M, int N, int K) {
  __shared__ float As[16][132];
  __shared__ float Bs[16][132];
  const int tid  = threadIdx.x;
  const int cg   = tid & 15;
  const int rg   = tid >> 4;
  const int sw   = (cg >> 2) & 1;          // spread b128 reads over odd+even quads
  const int colA = cg * 8 + sw * 4;
  const int colB = cg * 8 + (sw ^ 1) * 4;
  const int m0   = blockIdx.x * 128;
  const int n0   = blockIdx.y * 128;

  const int arow = tid >> 2;               // 0..63
  const int akq  = (tid & 3) * 4;
  const int bk   = tid >> 5;               // 0..7
  const int bn   = (tid & 31) * 4;

  const float* Ap0 = A + (size_t)(m0 + arow) * K + akq;
  const float* Ap1 = A + (size_t)(m0 + arow + 64) * K + akq;
  const float* Wp0 = W + (size_t)bk * N + n0 + bn;
  const float* Wp1 = W + (size_t)(bk + 8) * N + n0 + bn;

  float acc[8][8];
#pragma unroll
  for (int i = 0; i < 8; ++i)
#pragma unroll
    for (int j = 0; j < 8; ++j) acc[i][j] = 0.f;

  float4 av0, av1, bv0, bv1;
  av0 = *reinterpret_cast<const float4*>(Ap0);
  av1 = *reinterpret_cast<const float4*>(Ap1);
  bv0 = *reinterpret_cast<const float4*>(Wp0);
  bv1 = *reinterpret_cast<const float4*>(Wp1);

  auto write_tile = [&]() {
    As[akq + 0][arow] = av0.x; As[akq + 1][arow] = av0.y;
    As[akq + 2][arow] = av0.z; As[akq + 3][arow] = av0.w;
    As[akq + 0][arow + 64] = av1.x; As[akq + 1][arow + 64] = av1.y;
    As[akq + 2][arow + 64] = av1.z; As[akq + 3][arow + 64] = av1.w;
    *reinterpret_cast<float4*>(&Bs[bk][bn])     = bv0;
    *reinterpret_cast<float4*>(&Bs[bk + 8][bn]) = bv1;
  };
  auto compute_tile = [&]() {
#pragma unroll
    for (int kk = 0; kk < 16; ++kk) {
      float4 a0 = *reinterpret_cast<const float4*>(&As[kk][rg * 8]);
      float4 a1 = *reinterpret_cast<const float4*>(&As[kk][rg * 8 + 4]);
      float4 b0 = *reinterpret_cast<const float4*>(&Bs[kk][colA]);
      float4 b1 = *reinterpret_cast<const float4*>(&Bs[kk][colB]);
      float rv[8] = {a0.x, a0.y, a0.z, a0.w, a1.x, a1.y, a1.z, a1.w};
      float cv[8] = {b0.x, b0.y, b0.z, b0.w, b1.x, b1.y, b1.z, b1.w};
#pragma unroll
      for (int i = 0; i < 8; ++i)
#pragma unroll
        for (int j = 0; j < 8; ++j)
          acc[i][j] = fmaf(rv[i], cv[j], acc[i][j]);
    }
  };

  write_tile();
  __syncthreads();
#pragma unroll 1
  for (int k0 = 16; k0 < K; k0 += 16) {
    av0 = *reinterpret_cast<const float4*>(Ap0 + k0);
    av1 = *reinterpret_cast<const float4*>(Ap1 + k0);
    bv0 = *reinterpret_cast<const float4*>(Wp0 + (size_t)k0 * N);
    bv1 = *reinterpret_cast<const float4*>(Wp1 + (size_t)k0 * N);
    compute_tile();
    __syncthreads();
    write_tile();
    __syncthreads();
  }
  compute_tile();

  float4 bA = *reinterpret_cast<const float4*>(&bias[n0 + colA]);
  float4 bB = *reinterpret_cast<const float4*>(&bias[n0 + colB]);
  float ba[8] = {bA.x, bA.y, bA.z, bA.w, bB.x, bB.y, bB.z, bB.w};
#pragma unroll
  for (int i = 0; i < 8; ++i) {
    size_t row = (size_t)(m0 + rg * 8 + i);
    float o[8];
#pragma unroll
    for (int j = 0; j < 8; ++j) {
      float v = __fadd_rn(acc[i][j], ba[j]);
      if (RELU) v = fmaxf(v, 0.f);
      o[j] = v;
    }
    float4 oA; oA.x = o[0]; oA.y = o[1]; oA.z = o[2]; oA.w = o[3];
    float4 oB; oB.x = o[4]; oB.y = o[5]; oB.z = o[6]; oB.w = o[7];
    *reinterpret_cast<float4*>(&C[row * N + n0 + colA]) = oA;
    *reinterpret_cast<float4*>(&C[row * N + n0 + colB]) = oB;
  }
}

// ---------------------------------------------------------------------------
// cnorm[l][k] = sum_d C[l][k][d]^2, numpy pairwise 8-acc order (unchanged).
// ---------------------------------------------------------------------------
__global__ void cnorm_f32(const float* __restrict__ cb, float* __restrict__ cn) {
  int i = blockIdx.x * blockDim.x + threadIdx.x;
  if (i >= NLAYERS * NK) return;
  const float* row = cb + (size_t)i * LAT;
  float r[8];
#pragma unroll
  for (int j = 0; j < 8; ++j) r[j] = 0.f;
#pragma unroll
  for (int t = 0; t < 8; ++t)
#pragma unroll
    for (int j = 0; j < 8; ++j) {
      float v = row[t * 8 + j];
      r[j] = __fadd_rn(r[j], __fmul_rn(v, v));
    }
  cn[i] = __fadd_rn(__fadd_rn(__fadd_rn(r[0], r[1]), __fadd_rn(r[2], r[3])),
                    __fadd_rn(__fadd_rn(r[4], r[5]), __fadd_rn(r[6], r[7])));
}

// ---------------------------------------------------------------------------
// Residual quantization. 128 rows/block, 256 threads, 3 layers fused.
// TM=8 rows x TN=8 codes per thread; chunk = 128 codes; single LDS codebook
// buffer with T14 register prefetch. Distances bit-identical to round 1.
// ---------------------------------------------------------------------------
__global__ __launch_bounds__(256, 2) void rq_f32(
    const float* __restrict__ zg,     // [B][64]  (== residuals layer-0 region)
    const float* __restrict__ cb,     // [3][2048][64]
    const float* __restrict__ cnorm,  // [3][2048]
    float* __restrict__ out_codes,    // [3][B] as float
    float* __restrict__ out_quant,    // [B][64]
    float* __restrict__ out_res) {    // [3][B][64]
  __shared__ float rT[LAT][132];      // [lat][row]
  __shared__ float cbT[LAT][132];     // [lat][code], 128 codes
  __shared__ float rnS[128];
  __shared__ int   selS[128];

  const int tid  = threadIdx.x;
  const int cg   = tid & 15;
  const int rg   = tid >> 4;
  const int row0 = blockIdx.x * 128;
  const int sw   = (cg >> 2) & 1;
  const int colA = cg * 8 + sw * 4;        // codes colA..+3 -> acc j=0..3
  const int colB = cg * 8 + (sw ^ 1) * 4;  // codes colB..+3 -> acc j=4..7

  float4 q[8];   // running quantized; owner: row = rg+16p, quad = cg

#pragma unroll 1
  for (int layer = 0; layer < NLAYERS; ++layer) {
    const float* cbL = cb + (size_t)layer * NK * LAT;
    const float* cnL = cnorm + (size_t)layer * NK;

    // ---- residual = z - quantized (np order); rT + out_res (skip layer 0,
    // enc2 already wrote z == residual0 there) ----
#pragma unroll
    for (int p = 0; p < 8; ++p) {
      int row = rg + 16 * p;
      float4 z4 = *reinterpret_cast<const float4*>(
          &zg[(size_t)(row0 + row) * LAT + cg * 4]);
      float4 r4;
      if (layer == 0) {
        r4 = z4;
      } else {
        r4.x = __fsub_rn(z4.x, q[p].x);
        r4.y = __fsub_rn(z4.y, q[p].y);
        r4.z = __fsub_rn(z4.z, q[p].z);
        r4.w = __fsub_rn(z4.w, q[p].w);
      }
      rT[cg * 4 + 0][row] = r4.x;
      rT[cg * 4 + 1][row] = r4.y;
      rT[cg * 4 + 2][row] = r4.z;
      rT[cg * 4 + 3][row] = r4.w;
      if (layer > 0)
        *reinterpret_cast<float4*>(
            &out_res[((size_t)layer * NB + row0 + row) * LAT + cg * 4]) = r4;
    }
    // ---- stage chunk 0 (codes 0..127) ----
#pragma unroll
    for (int p = 0; p < 8; ++p) {
      int code = rg + 16 * p;
      float4 v = *reinterpret_cast<const float4*>(&cbL[(size_t)code * LAT + cg * 4]);
      cbT[cg * 4 + 0][code] = v.x;
      cbT[cg * 4 + 1][code] = v.y;
      cbT[cg * 4 + 2][code] = v.z;
      cbT[cg * 4 + 3][code] = v.w;
    }
    __syncthreads();

    // ---- rnorm per row (numpy pairwise 8-acc) ----
    if (tid < 128) {
      int row = tid;
      float r8[8];
#pragma unroll
      for (int j = 0; j < 8; ++j) r8[j] = 0.f;
#pragma unroll
      for (int t = 0; t < 8; ++t)
#pragma unroll
        for (int j = 0; j < 8; ++j) {
          float v = rT[t * 8 + j][row];
          r8[j] = __fadd_rn(r8[j], __fmul_rn(v, v));
        }
      rnS[row] = __fadd_rn(
          __fadd_rn(__fadd_rn(r8[0], r8[1]), __fadd_rn(r8[2], r8[3])),
          __fadd_rn(__fadd_rn(r8[4], r8[5]), __fadd_rn(r8[6], r8[7])));
    }
    __syncthreads();

    float rnv[8];
#pragma unroll
    for (int i = 0; i < 8; ++i) rnv[i] = rnS[rg * 8 + i];

    float minv[8];
    int   mini[8];
#pragma unroll
    for (int i = 0; i < 8; ++i) { minv[i] = FLT_MAX; mini[i] = 0; }

#pragma unroll 1
    for (int ch = 0; ch < NK / 128; ++ch) {
      // T14: issue current-chunk cnorm + next-chunk codebook loads early
      float4 cnA = *reinterpret_cast<const float4*>(&cnL[ch * 128 + colA]);
      float4 cnB = *reinterpret_cast<const float4*>(&cnL[ch * 128 + colB]);
      float4 nv[8];
      const bool haveNext = (ch + 1) < NK / 128;
      if (haveNext) {
        const float* src = cbL + (size_t)(ch + 1) * 128 * LAT;
#pragma unroll
        for (int p = 0; p < 8; ++p)
          nv[p] = *reinterpret_cast<const float4*>(
              &src[(size_t)(rg + 16 * p) * LAT + cg * 4]);
      }

      // ---- dots: 8 rows x 8 codes over 64 lat ----
      float acc[8][8];
#pragma unroll
      for (int i = 0; i < 8; ++i)
#pragma unroll
        for (int j = 0; j < 8; ++j) acc[i][j] = 0.f;

#pragma unroll 2
      for (int lat = 0; lat < LAT; ++lat) {
        float4 r0 = *reinterpret_cast<const float4*>(&rT[lat][rg * 8]);
        float4 r1 = *reinterpret_cast<const float4*>(&rT[lat][rg * 8 + 4]);
        float4 c0 = *reinterpret_cast<const float4*>(&cbT[lat][colA]);
        float4 c1 = *reinterpret_cast<const float4*>(&cbT[lat][colB]);
        float rv[8] = {r0.x, r0.y, r0.z, r0.w, r1.x, r1.y, r1.z, r1.w};
        float cv[8] = {c0.x, c0.y, c0.z, c0.w, c1.x, c1.y, c1.z, c1.w};
#pragma unroll
        for (int i = 0; i < 8; ++i)
#pragma unroll
          for (int j = 0; j < 8; ++j)
            acc[i][j] = fmaf(rv[i], cv[j], acc[i][j]);
      }

      // ---- distances (round-1-identical expression) + tie-aware argmin ----
      const int kA = ch * 128 + colA;
      const int kB = ch * 128 + colB;
      float cna[4] = {cnA.x, cnA.y, cnA.z, cnA.w};
      float cnb[4] = {cnB.x, cnB.y, cnB.z, cnB.w};
#pragma unroll
      for (int i = 0; i < 8; ++i) {
#pragma unroll
        for (int j = 0; j < 4; ++j) {
          float d = __fadd_rn(__fsub_rn(rnv[i], __fmul_rn(2.0f, acc[i][j])),
                              cna[j]);
          int k = kA + j;
          bool t = (d < minv[i]) || (d == minv[i] && k < mini[i]);
          minv[i] = t ? d : minv[i];
          mini[i] = t ? k : mini[i];
        }
#pragma unroll
        for (int j = 0; j < 4; ++j) {
          float d = __fadd_rn(__fsub_rn(rnv[i], __fmul_rn(2.0f, acc[i][j + 4])),
                              cnb[j]);
          int k = kB + j;
          bool t = (d < minv[i]) || (d == minv[i] && k < mini[i]);
          minv[i] = t ? d : minv[i];
          mini[i] = t ? k : mini[i];
        }
      }
      __syncthreads();   // all reads of cbT done
      if (haveNext) {
#pragma unroll
        for (int p = 0; p < 8; ++p) {
          int code = rg + 16 * p;
          cbT[cg * 4 + 0][code] = nv[p].x;
          cbT[cg * 4 + 1][code] = nv[p].y;
          cbT[cg * 4 + 2][code] = nv[p].z;
          cbT[cg * 4 + 3][code] = nv[p].w;
        }
      }
      __syncthreads();   // cbT ready
    }

    // ---- reduce argmin across the 16 cg lanes (smallest-index tie-break) ----
#pragma unroll
    for (int i = 0; i < 8; ++i) {
      float v = minv[i]; int idx = mini[i];
#pragma unroll
      for (int m = 8; m >= 1; m >>= 1) {
        float ov = __shfl_xor(v, m, 64);
        int   oi = __shfl_xor(idx, m, 64);
        if (ov < v || (ov == v && oi < idx)) { v = ov; idx = oi; }
      }
      if (cg == 0) {
        selS[rg * 8 + i] = idx;
        out_codes[(size_t)layer * NB + row0 + rg * 8 + i] = (float)idx;
      }
    }
    __syncthreads();

    // ---- quantized = C[code] + quantized (np order) ----
#pragma unroll
    for (int p = 0; p < 8; ++p) {
      int row  = rg + 16 * p;
      int code = selS[row];
      float4 cv = *reinterpret_cast<const float4*>(
          &cbL[(size_t)code * LAT + cg * 4]);
      if (layer == 0) {
        q[p] = cv;
      } else {
        q[p].x = __fadd_rn(cv.x, q[p].x);
        q[p].y = __fadd_rn(cv.y, q[p].y);
        q[p].z = __fadd_rn(cv.z, q[p].z);
        q[p].w = __fadd_rn(cv.w, q[p].w);
      }
    }
    __syncthreads();
  }

#pragma unroll
  for (int p = 0; p < 8; ++p) {
    int row = rg + 16 * p;
    *reinterpret_cast<float4*>(
        &out_quant[(size_t)(row0 + row) * LAT + cg * 4]) = q[p];
  }
}

// ---------------------------------------------------------------------------
extern "C" void kernel_launch(void* const* d_in, const int* in_sizes, int n_in,
                              void* d_out, int out_size, void* d_ws, size_t ws_size,
                              hipStream_t stream) {
  (void)in_sizes; (void)n_in; (void)out_size; (void)ws_size;
  const float* x   = (const float*)d_in[0];
  const float* ew1 = (const float*)d_in[1];
  const float* eb1 = (const float*)d_in[2];
  const float* ew2 = (const float*)d_in[3];
  const float* eb2 = (const float*)d_in[4];
  const float* cbk = (const float*)d_in[5];
  const float* dw1 = (const float*)d_in[6];
  const float* db1 = (const float*)d_in[7];
  const float* dw2 = (const float*)d_in[8];
  const float* db2 = (const float*)d_in[9];

  float* out     = (float*)d_out;
  float* o_codes = out;                                   // 3*B
  float* o_xrec  = out + (size_t)NLAYERS * NB;            // B*512
  float* o_quant = o_xrec + (size_t)NB * IN_DIM;          // B*64
  float* o_res   = o_quant + (size_t)NB * LAT;            // 3*B*64

  float* h  = (float*)d_ws;                               // B*256 fp32
  float* cn = h + (size_t)NB * HID;                       // 3*2048 fp32

  cnorm_f32<<<(NLAYERS * NK + 255) / 256, 256, 0, stream>>>(cbk, cn);
  // encoder
  gemm128<true ><<<dim3(NB / 128, HID / 128),    256, 0, stream>>>(x, ew1, eb1, h,     NB, HID,    IN_DIM);
  gemm_f32<false><<<dim3(NB / 128, LAT / 64),    256, 0, stream>>>(h, ew2, eb2, o_res, NB, LAT,    HID);
  // residual quantization (z lives in residuals[0] region; rq leaves it as-is)
  rq_f32<<<NB / 128, 256, 0, stream>>>(o_res, cbk, cn, o_codes, o_quant, o_res);
  // decoder
  gemm128<true ><<<dim3(NB / 128, HID / 128),    256, 0, stream>>>(o_quant, dw1, db1, h,      NB, HID,    LAT);
  gemm128<false><<<dim3(NB / 128, IN_DIM / 128), 256, 0, stream>>>(h,       dw2, db2, o_xrec, NB, IN_DIM, HID);
}

// Round 3
// 825.227 us; speedup vs baseline: 1.6090x; 1.5717x over previous
//
#include <hip/hip_runtime.h>
#include <float.h>

#define NB      65536
#define IN_DIM  512
#define HID     256
#define LAT     64
#define NLAYERS 3
#define NK      2048
#define DELTA   1e-2f

typedef __attribute__((ext_vector_type(8)))  short s16x8;   // 8 bf16 (4 VGPR)
typedef __attribute__((ext_vector_type(16))) float fp32x16; // MFMA 32x32 acc

__device__ __forceinline__ unsigned short f2bf(float v) {  // fp32 -> bf16 RNE
  unsigned u = __float_as_uint(v);
  unsigned r = (u + 0x7fffu + ((u >> 16) & 1u)) >> 16;
  return (unsigned short)r;
}
__device__ __forceinline__ float bf2f(unsigned short h) {
  return __uint_as_float((unsigned)h << 16);
}

// ---------------------------------------------------------------------------
// enc2-style GEMM (N=64): BM=128, BN=64, BK=32, TM=8, TN=4. (bit-exact np)
// ---------------------------------------------------------------------------
template<bool RELU>
__global__ __launch_bounds__(256) void gemm_f32(
    const float* __restrict__ A, const float* __restrict__ W,
    const float* __restrict__ bias, float* __restrict__ C,
    int M, int N, int K) {
  __shared__ float As[32][132];
  __shared__ float Bs[32][64];
  const int tid = threadIdx.x;
  const int cg  = tid & 15;
  const int rg  = tid >> 4;
  const int m0  = blockIdx.x * 128;
  const int n0  = blockIdx.y * 64;

  float acc[8][4];
#pragma unroll
  for (int i = 0; i < 8; ++i)
#pragma unroll
    for (int j = 0; j < 4; ++j) acc[i][j] = 0.f;

  for (int k0 = 0; k0 < K; k0 += 32) {
#pragma unroll
    for (int p = 0; p < 4; ++p) {
      int a = tid + p * 256;
      int row = a >> 3, kq = (a & 7) * 4;
      float4 v = *reinterpret_cast<const float4*>(&A[(size_t)(m0 + row) * K + k0 + kq]);
      As[kq + 0][row] = v.x; As[kq + 1][row] = v.y;
      As[kq + 2][row] = v.z; As[kq + 3][row] = v.w;
    }
#pragma unroll
    for (int p = 0; p < 2; ++p) {
      int a = tid + p * 256;
      int kk = a >> 4, nq = (a & 15) * 4;
      *reinterpret_cast<float4*>(&Bs[kk][nq]) =
          *reinterpret_cast<const float4*>(&W[(size_t)(k0 + kk) * N + n0 + nq]);
    }
    __syncthreads();
#pragma unroll
    for (int kk = 0; kk < 32; ++kk) {
      float4 a0 = *reinterpret_cast<const float4*>(&As[kk][rg * 8]);
      float4 a1 = *reinterpret_cast<const float4*>(&As[kk][rg * 8 + 4]);
      float4 b0 = *reinterpret_cast<const float4*>(&Bs[kk][cg * 4]);
      float av[8] = {a0.x, a0.y, a0.z, a0.w, a1.x, a1.y, a1.z, a1.w};
      float bv[4] = {b0.x, b0.y, b0.z, b0.w};
#pragma unroll
      for (int i = 0; i < 8; ++i)
#pragma unroll
        for (int j = 0; j < 4; ++j)
          acc[i][j] = fmaf(av[i], bv[j], acc[i][j]);
    }
    __syncthreads();
  }

  float4 bb = *reinterpret_cast<const float4*>(&bias[n0 + cg * 4]);
  float bv[4] = {bb.x, bb.y, bb.z, bb.w};
#pragma unroll
  for (int i = 0; i < 8; ++i) {
    float vals[4];
#pragma unroll
    for (int j = 0; j < 4; ++j) {
      float v = __fadd_rn(acc[i][j], bv[j]);
      if (RELU) v = fmaxf(v, 0.f);
      vals[j] = v;
    }
    float4 o; o.x = vals[0]; o.y = vals[1]; o.z = vals[2]; o.w = vals[3];
    *reinterpret_cast<float4*>(&C[(size_t)(m0 + rg * 8 + i) * N + n0 + cg * 4]) = o;
  }
}

// ---------------------------------------------------------------------------
// Big GEMM: BM=128, BN=128, BK=16, TM=8, TN=8. (bit-exact np, unchanged)
// ---------------------------------------------------------------------------
template<bool RELU>
__global__ __launch_bounds__(256) void gemm128(
    const float* __restrict__ A, const float* __restrict__ W,
    const float* __restrict__ bias, float* __restrict__ C,
    int M, int N, int K) {
  __shared__ float As[16][132];
  __shared__ float Bs[16][132];
  const int tid  = threadIdx.x;
  const int cg   = tid & 15;
  const int rg   = tid >> 4;
  const int sw   = (cg >> 2) & 1;
  const int colA = cg * 8 + sw * 4;
  const int colB = cg * 8 + (sw ^ 1) * 4;
  const int m0   = blockIdx.x * 128;
  const int n0   = blockIdx.y * 128;

  const int arow = tid >> 2;
  const int akq  = (tid & 3) * 4;
  const int bk   = tid >> 5;
  const int bn   = (tid & 31) * 4;

  const float* Ap0 = A + (size_t)(m0 + arow) * K + akq;
  const float* Ap1 = A + (size_t)(m0 + arow + 64) * K + akq;
  const float* Wp0 = W + (size_t)bk * N + n0 + bn;
  const float* Wp1 = W + (size_t)(bk + 8) * N + n0 + bn;

  float acc[8][8];
#pragma unroll
  for (int i = 0; i < 8; ++i)
#pragma unroll
    for (int j = 0; j < 8; ++j) acc[i][j] = 0.f;

  float4 av0, av1, bv0, bv1;
  av0 = *reinterpret_cast<const float4*>(Ap0);
  av1 = *reinterpret_cast<const float4*>(Ap1);
  bv0 = *reinterpret_cast<const float4*>(Wp0);
  bv1 = *reinterpret_cast<const float4*>(Wp1);

  auto write_tile = [&]() {
    As[akq + 0][arow] = av0.x; As[akq + 1][arow] = av0.y;
    As[akq + 2][arow] = av0.z; As[akq + 3][arow] = av0.w;
    As[akq + 0][arow + 64] = av1.x; As[akq + 1][arow + 64] = av1.y;
    As[akq + 2][arow + 64] = av1.z; As[akq + 3][arow + 64] = av1.w;
    *reinterpret_cast<float4*>(&Bs[bk][bn])     = bv0;
    *reinterpret_cast<float4*>(&Bs[bk + 8][bn]) = bv1;
  };
  auto compute_tile = [&]() {
#pragma unroll
    for (int kk = 0; kk < 16; ++kk) {
      float4 a0 = *reinterpret_cast<const float4*>(&As[kk][rg * 8]);
      float4 a1 = *reinterpret_cast<const float4*>(&As[kk][rg * 8 + 4]);
      float4 b0 = *reinterpret_cast<const float4*>(&Bs[kk][colA]);
      float4 b1 = *reinterpret_cast<const float4*>(&Bs[kk][colB]);
      float rv[8] = {a0.x, a0.y, a0.z, a0.w, a1.x, a1.y, a1.z, a1.w};
      float cv[8] = {b0.x, b0.y, b0.z, b0.w, b1.x, b1.y, b1.z, b1.w};
#pragma unroll
      for (int i = 0; i < 8; ++i)
#pragma unroll
        for (int j = 0; j < 8; ++j)
          acc[i][j] = fmaf(rv[i], cv[j], acc[i][j]);
    }
  };

  write_tile();
  __syncthreads();
#pragma unroll 1
  for (int k0 = 16; k0 < K; k0 += 16) {
    av0 = *reinterpret_cast<const float4*>(Ap0 + k0);
    av1 = *reinterpret_cast<const float4*>(Ap1 + k0);
    bv0 = *reinterpret_cast<const float4*>(Wp0 + (size_t)k0 * N);
    bv1 = *reinterpret_cast<const float4*>(Wp1 + (size_t)k0 * N);
    compute_tile();
    __syncthreads();
    write_tile();
    __syncthreads();
  }
  compute_tile();

  float4 bA = *reinterpret_cast<const float4*>(&bias[n0 + colA]);
  float4 bB = *reinterpret_cast<const float4*>(&bias[n0 + colB]);
  float ba[8] = {bA.x, bA.y, bA.z, bA.w, bB.x, bB.y, bB.z, bB.w};
#pragma unroll
  for (int i = 0; i < 8; ++i) {
    size_t row = (size_t)(m0 + rg * 8 + i);
    float o[8];
#pragma unroll
    for (int j = 0; j < 8; ++j) {
      float v = __fadd_rn(acc[i][j], ba[j]);
      if (RELU) v = fmaxf(v, 0.f);
      o[j] = v;
    }
    float4 oA; oA.x = o[0]; oA.y = o[1]; oA.z = o[2]; oA.w = o[3];
    float4 oB; oB.x = o[4]; oB.y = o[5]; oB.z = o[6]; oB.w = o[7];
    *reinterpret_cast<float4*>(&C[row * N + n0 + colA]) = oA;
    *reinterpret_cast<float4*>(&C[row * N + n0 + colB]) = oB;
  }
}

// ---------------------------------------------------------------------------
// cnorm[l][k] = sum_d C[l][k][d]^2, numpy pairwise 8-acc order.
// ---------------------------------------------------------------------------
__global__ void cnorm_f32(const float* __restrict__ cb, float* __restrict__ cn) {
  int i = blockIdx.x * blockDim.x + threadIdx.x;
  if (i >= NLAYERS * NK) return;
  const float* row = cb + (size_t)i * LAT;
  float r[8];
#pragma unroll
  for (int j = 0; j < 8; ++j) r[j] = 0.f;
#pragma unroll
  for (int t = 0; t < 8; ++t)
#pragma unroll
    for (int j = 0; j < 8; ++j) {
      float v = row[t * 8 + j];
      r[j] = __fadd_rn(r[j], __fmul_rn(v, v));
    }
  cn[i] = __fadd_rn(__fadd_rn(__fadd_rn(r[0], r[1]), __fadd_rn(r[2], r[3])),
                    __fadd_rn(__fadd_rn(r[4], r[5]), __fadd_rn(r[6], r[7])));
}

// ---------------------------------------------------------------------------
// Precompute codebook bf16 hi/lo splits in MFMA-frag-linear layout.
// Frag element: code = ch*64 + nt*32 + (lane&31), k = ks*16 + (lane>>5)*8 + i.
// Storage elem offset: ((((layer*32+ch)*8 + nt*4+ks)*2 + hl)*64 + lane)*8 + i.
// ---------------------------------------------------------------------------
__global__ void split_cb(const float* __restrict__ cb,
                         unsigned short* __restrict__ cbf) {
  const int sid  = blockIdx.x * 256 + threadIdx.x;   // 0 .. 49151
  const int lane = sid & 63;
  const int grp  = sid >> 6;        // (layer*32+ch)*8 + fg
  const int fg   = grp & 7;
  const int chl  = grp >> 3;        // layer*32 + ch
  const int nt = fg >> 2, ks = fg & 3;
  const int layer = chl >> 5, ch = chl & 31;
  const int code = ch * 64 + nt * 32 + (lane & 31);
  const int k0 = ks * 16 + (lane >> 5) * 8;
  const float* src = cb + ((size_t)layer * NK + code) * LAT + k0;
  float4 a = *(const float4*)src;
  float4 b = *(const float4*)(src + 4);
  float v[8] = {a.x, a.y, a.z, a.w, b.x, b.y, b.z, b.w};
  s16x8 hi, lo;
#pragma unroll
  for (int i = 0; i < 8; ++i) {
    unsigned short h = f2bf(v[i]);
    hi[i] = (short)h;
    lo[i] = (short)f2bf(__fsub_rn(v[i], bf2f(h)));
  }
  *(s16x8*)(cbf + ((size_t)grp * 2 + 0) * 512 + lane * 8) = hi;
  *(s16x8*)(cbf + ((size_t)grp * 2 + 1) * 512 + lane * 8) = lo;
}

// ---------------------------------------------------------------------------
// Residual quantization via split-bf16 MFMA + exact numpy rescue.
// Block: 256 thr = 4 waves; rows/block = 128. Wave w: row-group w>>1 (64 rows,
// 2 M-subtiles of 32), code-half w&1 (16 chunks of 64 codes). B-frags read
// directly from frag-linear global (L2-hot). Per-lane best-2 tracking; window
// Δ-rescue recomputes exact np distances; flagged rows -> full exact scan.
// ---------------------------------------------------------------------------
__global__ __launch_bounds__(256, 2) void rq_mfma(
    const float* __restrict__ zg,            // [B][64] == out_res layer 0 (z)
    const float* __restrict__ cb,            // [3][2048][64] fp32
    const unsigned short* __restrict__ cbf,  // frag-linear bf16 splits
    const float* __restrict__ cnorm,         // [3][2048]
    float* __restrict__ out_codes,           // [3][B] as float
    float* __restrict__ out_quant,           // [B][64]
    float* __restrict__ out_res) {           // [3][B][64]
  __shared__ float m1S[128][2];
  __shared__ int   candS[128][8];
  __shared__ int   cntS[128][2];
  __shared__ int   flagS[128][2];
  __shared__ int   selS[128];
  __shared__ float rnS[128];
  __shared__ float bestD[256];
  __shared__ int   bestK[256];

  const int tid   = threadIdx.x;
  const int w     = tid >> 6;
  const int rgrp  = w >> 1;       // rows rgrp*64 ..
  const int chalf = w & 1;        // chunks chalf*16 ..
  const int lane  = tid & 63;
  const int half  = lane >> 5;
  const int lcol  = lane & 31;
  const int rb0   = blockIdx.x * 128;

  s16x8 ah[2][4], al[2][4];       // residual splits, [Msub][kstep]

  for (int layer = 0; layer < NLAYERS; ++layer) {
    const float* cbL = cb + (size_t)layer * NK * LAT;
    const float* cnL = cnorm + (size_t)layer * NK;
    const unsigned short* cbfL = cbf + (size_t)layer * (NK * LAT * 2);
    float* resL = out_res + (size_t)layer * NB * LAT;

    // ---- P0: residual = z - q (np order), write out_res, build splits ----
#pragma unroll
    for (int m = 0; m < 2; ++m) {
      const size_t row = (size_t)(rb0 + rgrp * 64 + m * 32 + lcol);
#pragma unroll
      for (int ks = 0; ks < 4; ++ks) {
        const int k0 = ks * 16 + half * 8;
        const float* zp = zg + row * LAT + k0;
        float4 a = *(const float4*)zp;
        float4 b = *(const float4*)(zp + 4);
        float r[8] = {a.x, a.y, a.z, a.w, b.x, b.y, b.z, b.w};
        if (layer > 0) {
          const float* qp = out_quant + row * LAT + k0;
          float4 qa = *(const float4*)qp;
          float4 qb = *(const float4*)(qp + 4);
          float q[8] = {qa.x, qa.y, qa.z, qa.w, qb.x, qb.y, qb.z, qb.w};
#pragma unroll
          for (int i = 0; i < 8; ++i) r[i] = __fsub_rn(r[i], q[i]);
          if (chalf == 0) {
            float4 o0 = {r[0], r[1], r[2], r[3]};
            float4 o1 = {r[4], r[5], r[6], r[7]};
            *(float4*)(resL + row * LAT + k0) = o0;
            *(float4*)(resL + row * LAT + k0 + 4) = o1;
          }
        }
#pragma unroll
        for (int i = 0; i < 8; ++i) {
          unsigned short hh = f2bf(r[i]);
          float hf = bf2f(hh);
          ah[m][ks][i] = (short)hh;
          al[m][ks][i] = (short)f2bf(__fsub_rn(r[i], hf));
        }
      }
    }
    __syncthreads();   // resL visible for rnorm / rescue

    // ---- P1: row norms (numpy pairwise 8-acc) ----
    if (tid < 128) {
      const float* rp = resL + (size_t)(rb0 + tid) * LAT;
      float r8[8] = {0.f, 0.f, 0.f, 0.f, 0.f, 0.f, 0.f, 0.f};
#pragma unroll
      for (int tb = 0; tb < 8; ++tb) {
        float4 x0 = *(const float4*)(rp + tb * 8);
        float4 x1 = *(const float4*)(rp + tb * 8 + 4);
        float v[8] = {x0.x, x0.y, x0.z, x0.w, x1.x, x1.y, x1.z, x1.w};
#pragma unroll
        for (int j = 0; j < 8; ++j)
          r8[j] = __fadd_rn(r8[j], __fmul_rn(v[j], v[j]));
      }
      rnS[tid] = __fadd_rn(
          __fadd_rn(__fadd_rn(r8[0], r8[1]), __fadd_rn(r8[2], r8[3])),
          __fadd_rn(__fadd_rn(r8[4], r8[5]), __fadd_rn(r8[6], r8[7])));
    }

    // ---- P2: approximate distances via MFMA, per-lane best-2 tracking ----
    float v1[2][16], v2[2][16];
    int   i1[2][16];
#pragma unroll
    for (int m = 0; m < 2; ++m)
#pragma unroll
      for (int r = 0; r < 16; ++r) {
        v1[m][r] = FLT_MAX; v2[m][r] = FLT_MAX; i1[m][r] = 0;
      }

#pragma unroll 1
    for (int ch = 0; ch < 16; ++ch) {
      const int chg = chalf * 16 + ch;
      const unsigned short* cf = cbfL + (size_t)chg * 8192;
#pragma unroll
      for (int nt = 0; nt < 2; ++nt) {
        const int kbase = chg * 64 + nt * 32 + lcol;
        float cnv = cnL[kbase];
        s16x8 bh[4], bl[4];
#pragma unroll
        for (int ks = 0; ks < 4; ++ks) {
          bh[ks] = *(const s16x8*)(cf + ((size_t)((nt * 4 + ks) * 2 + 0) * 64 + lane) * 8);
          bl[ks] = *(const s16x8*)(cf + ((size_t)((nt * 4 + ks) * 2 + 1) * 64 + lane) * 8);
        }
        fp32x16 acc0, acc1;
#pragma unroll
        for (int r = 0; r < 16; ++r) { acc0[r] = 0.f; acc1[r] = 0.f; }
#pragma unroll
        for (int ks = 0; ks < 4; ++ks) {
          acc0 = __builtin_amdgcn_mfma_f32_32x32x16_bf16(ah[0][ks], bh[ks], acc0, 0, 0, 0);
          acc1 = __builtin_amdgcn_mfma_f32_32x32x16_bf16(ah[1][ks], bh[ks], acc1, 0, 0, 0);
          acc0 = __builtin_amdgcn_mfma_f32_32x32x16_bf16(ah[0][ks], bl[ks], acc0, 0, 0, 0);
          acc1 = __builtin_amdgcn_mfma_f32_32x32x16_bf16(ah[1][ks], bl[ks], acc1, 0, 0, 0);
          acc0 = __builtin_amdgcn_mfma_f32_32x32x16_bf16(al[0][ks], bh[ks], acc0, 0, 0, 0);
          acc1 = __builtin_amdgcn_mfma_f32_32x32x16_bf16(al[1][ks], bh[ks], acc1, 0, 0, 0);
        }
#pragma unroll
        for (int r = 0; r < 16; ++r) {
          float d0 = fmaf(-2.f, acc0[r], cnv);
          bool c0 = d0 < v1[0][r];
          v2[0][r] = c0 ? v1[0][r] : fminf(v2[0][r], d0);
          v1[0][r] = c0 ? d0 : v1[0][r];
          i1[0][r] = c0 ? kbase : i1[0][r];
          float d1 = fmaf(-2.f, acc1[r], cnv);
          bool c1 = d1 < v1[1][r];
          v2[1][r] = c1 ? v1[1][r] : fminf(v2[1][r], d1);
          v1[1][r] = c1 ? d1 : v1[1][r];
          i1[1][r] = c1 ? kbase : i1[1][r];
        }
      }
    }

    // ---- P3: merged selection across the two code-half waves ----
#pragma unroll
    for (int m = 0; m < 2; ++m)
#pragma unroll
      for (int r = 0; r < 16; ++r) {
        float m1 = v1[m][r];
        m1 = fminf(m1, __shfl_xor(m1, 1));
        m1 = fminf(m1, __shfl_xor(m1, 2));
        m1 = fminf(m1, __shfl_xor(m1, 4));
        m1 = fminf(m1, __shfl_xor(m1, 8));
        m1 = fminf(m1, __shfl_xor(m1, 16));
        const int rowloc = rgrp * 64 + m * 32 + (r & 3) + 8 * (r >> 2) + 4 * half;
        if (lcol == 0) m1S[rowloc][chalf] = m1;
      }
    __syncthreads();
#pragma unroll
    for (int m = 0; m < 2; ++m)
#pragma unroll
      for (int r = 0; r < 16; ++r) {
        const int rowloc = rgrp * 64 + m * 32 + (r & 3) + 8 * (r >> 2) + 4 * half;
        float thr = fminf(m1S[rowloc][0], m1S[rowloc][1]) + DELTA;
        unsigned long long bc = __ballot(v1[m][r] <= thr);
        unsigned long long bf = __ballot(v2[m][r] <= thr);
        unsigned mc = (unsigned)(bc >> (half * 32));
        unsigned mf = (unsigned)(bf >> (half * 32));
        int pos = __popc(mc & ((1u << lcol) - 1u));
        if (v1[m][r] <= thr && pos < 4) candS[rowloc][chalf * 4 + pos] = i1[m][r];
        if (lcol == 0) {
          int c = __popc(mc);
          cntS[rowloc][chalf]  = (c < 4) ? c : 4;
          flagS[rowloc][chalf] = (mf != 0u) || (c > 4);
        }
      }
    __syncthreads();

    // ---- Phase A: exact np recompute for candidates (unflagged rows) ----
    if (tid < 128) {
      const int t = tid;
      if ((flagS[t][0] | flagS[t][1]) == 0) {
        const float* rp = resL + (size_t)(rb0 + t) * LAT;
        float rr[64];
#pragma unroll
        for (int j = 0; j < 16; ++j) {
          float4 x = *(const float4*)(rp + j * 4);
          rr[j * 4 + 0] = x.x; rr[j * 4 + 1] = x.y;
          rr[j * 4 + 2] = x.z; rr[j * 4 + 3] = x.w;
        }
        const float rn = rnS[t];
        float bd = FLT_MAX; int bk = 0x7fffffff;
        const int c0 = cntS[t][0], c1n = cntS[t][1];
        for (int c = 0; c < c0 + c1n; ++c) {
          int k = candS[t][(c < c0) ? c : (4 + c - c0)];
          const float* cp = cbL + (size_t)k * LAT;
          float dot = 0.f;
#pragma unroll
          for (int j = 0; j < 64; ++j) dot = fmaf(rr[j], cp[j], dot);
          float d = __fadd_rn(__fsub_rn(rn, __fmul_rn(2.f, dot)), cnL[k]);
          if (d < bd || (d == bd && k < bk)) { bd = d; bk = k; }
        }
        selS[t] = bk;
        out_codes[(size_t)layer * NB + rb0 + t] = (float)bk;
      }
    }
    __syncthreads();

    // ---- Phase B: flagged rows -> full exact scan (rare) ----
#pragma unroll 1
    for (int t2 = 0; t2 < 128; ++t2) {
      if ((flagS[t2][0] | flagS[t2][1]) == 0) continue;
      const float* rp = resL + (size_t)(rb0 + t2) * LAT;
      const float rn = rnS[t2];
      float bd = FLT_MAX; int bk = 0x7fffffff;
#pragma unroll 1
      for (int j = 0; j < 8; ++j) {
        int k = tid * 8 + j;
        const float* cp = cbL + (size_t)k * LAT;
        float dot = 0.f;
        for (int q = 0; q < 64; ++q) dot = fmaf(rp[q], cp[q], dot);
        float d = __fadd_rn(__fsub_rn(rn, __fmul_rn(2.f, dot)), cnL[k]);
        if (d < bd || (d == bd && k < bk)) { bd = d; bk = k; }
      }
      bestD[tid] = bd; bestK[tid] = bk;
      __syncthreads();
      if (tid == 0) {
        float gd = FLT_MAX; int gk = 0x7fffffff;
        for (int i = 0; i < 256; ++i) {
          float d = bestD[i]; int k = bestK[i];
          if (d < gd || (d == gd && k < gk)) { gd = d; gk = k; }
        }
        selS[t2] = gk;
        out_codes[(size_t)layer * NB + rb0 + t2] = (float)gk;
      }
      __syncthreads();
    }

    // ---- Phase Q: quantized = C[code] + quantized (np order), global RMW ----
    if (chalf == 0) {
#pragma unroll
      for (int m = 0; m < 2; ++m) {
        const int rowloc = rgrp * 64 + m * 32 + lcol;
        const size_t row = (size_t)(rb0 + rowloc);
        const int sel = selS[rowloc];
        const float* cp = cbL + (size_t)sel * LAT;
#pragma unroll
        for (int ks = 0; ks < 4; ++ks) {
          const int k0 = ks * 16 + half * 8;
          float4 c0 = *(const float4*)(cp + k0);
          float4 c1 = *(const float4*)(cp + k0 + 4);
          float* qp = out_quant + row * LAT + k0;
          if (layer == 0) {
            *(float4*)qp = c0; *(float4*)(qp + 4) = c1;
          } else {
            float4 q0 = *(const float4*)qp;
            float4 q1 = *(const float4*)(qp + 4);
            q0.x = __fadd_rn(c0.x, q0.x); q0.y = __fadd_rn(c0.y, q0.y);
            q0.z = __fadd_rn(c0.z, q0.z); q0.w = __fadd_rn(c0.w, q0.w);
            q1.x = __fadd_rn(c1.x, q1.x); q1.y = __fadd_rn(c1.y, q1.y);
            q1.z = __fadd_rn(c1.z, q1.z); q1.w = __fadd_rn(c1.w, q1.w);
            *(float4*)qp = q0; *(float4*)(qp + 4) = q1;
          }
        }
      }
    }
    __syncthreads();   // q visible to all waves for next layer's P0
  }
}

// ---------------------------------------------------------------------------
extern "C" void kernel_launch(void* const* d_in, const int* in_sizes, int n_in,
                              void* d_out, int out_size, void* d_ws, size_t ws_size,
                              hipStream_t stream) {
  (void)in_sizes; (void)n_in; (void)out_size; (void)ws_size;
  const float* x   = (const float*)d_in[0];
  const float* ew1 = (const float*)d_in[1];
  const float* eb1 = (const float*)d_in[2];
  const float* ew2 = (const float*)d_in[3];
  const float* eb2 = (const float*)d_in[4];
  const float* cbk = (const float*)d_in[5];
  const float* dw1 = (const float*)d_in[6];
  const float* db1 = (const float*)d_in[7];
  const float* dw2 = (const float*)d_in[8];
  const float* db2 = (const float*)d_in[9];

  float* out     = (float*)d_out;
  float* o_codes = out;                                   // 3*B
  float* o_xrec  = out + (size_t)NLAYERS * NB;            // B*512
  float* o_quant = o_xrec + (size_t)NB * IN_DIM;          // B*64
  float* o_res   = o_quant + (size_t)NB * LAT;            // 3*B*64

  float* h  = (float*)d_ws;                               // B*256 fp32
  float* cn = h + (size_t)NB * HID;                       // 3*2048 fp32
  // codebook frag splits live in the (dead until dec2) tail of o_xrec:
  // written by split_cb, read by rq_mfma, overwritten by dec2 each call.
  unsigned short* cbf = (unsigned short*)(o_xrec + (size_t)16 * 1024 * 1024);

  cnorm_f32<<<(NLAYERS * NK + 255) / 256, 256, 0, stream>>>(cbk, cn);
  split_cb<<<192, 256, 0, stream>>>(cbk, cbf);
  // encoder (bit-exact fp32)
  gemm128<true ><<<dim3(NB / 128, HID / 128),    256, 0, stream>>>(x, ew1, eb1, h,     NB, HID,    IN_DIM);
  gemm_f32<false><<<dim3(NB / 128, LAT / 64),    256, 0, stream>>>(h, ew2, eb2, o_res, NB, LAT,    HID);
  // residual quantization (MFMA approx + exact rescue)
  rq_mfma<<<NB / 128, 256, 0, stream>>>(o_res, cbk, cbf, cn, o_codes, o_quant, o_res);
  // decoder (bit-exact fp32)
  gemm128<true ><<<dim3(NB / 128, HID / 128),    256, 0, stream>>>(o_quant, dw1, db1, h,      NB, HID,    LAT);
  gemm128<false><<<dim3(NB / 128, IN_DIM / 128), 256, 0, stream>>>(h,       dw2, db2, o_xrec, NB, IN_DIM, HID);
}

// Round 4
// 800.302 us; speedup vs baseline: 1.6591x; 1.0311x over previous
//
#include <hip/hip_runtime.h>
#include <float.h>

#define NB      65536
#define IN_DIM  512
#define HID     256
#define LAT     64
#define NLAYERS 3
#define NK      2048
#define DELTA   1e-2f

typedef __attribute__((ext_vector_type(8)))  short s16x8;   // 8 bf16 (4 VGPR)
typedef __attribute__((ext_vector_type(16))) float fp32x16; // MFMA 32x32 acc

__device__ __forceinline__ unsigned short f2bf(float v) {  // fp32 -> bf16 RNE
  unsigned u = __float_as_uint(v);
  unsigned r = (u + 0x7fffu + ((u >> 16) & 1u)) >> 16;
  return (unsigned short)r;
}
__device__ __forceinline__ float bf2f(unsigned short h) {
  return __uint_as_float((unsigned)h << 16);
}

// ---------------------------------------------------------------------------
// enc2-style GEMM (N=64): BM=128, BN=64, BK=32, TM=8, TN=4. (bit-exact np)
// ---------------------------------------------------------------------------
template<bool RELU>
__global__ __launch_bounds__(256) void gemm_f32(
    const float* __restrict__ A, const float* __restrict__ W,
    const float* __restrict__ bias, float* __restrict__ C,
    int M, int N, int K) {
  __shared__ float As[32][132];
  __shared__ float Bs[32][64];
  const int tid = threadIdx.x;
  const int cg  = tid & 15;
  const int rg  = tid >> 4;
  const int m0  = blockIdx.x * 128;
  const int n0  = blockIdx.y * 64;

  float acc[8][4];
#pragma unroll
  for (int i = 0; i < 8; ++i)
#pragma unroll
    for (int j = 0; j < 4; ++j) acc[i][j] = 0.f;

  for (int k0 = 0; k0 < K; k0 += 32) {
#pragma unroll
    for (int p = 0; p < 4; ++p) {
      int a = tid + p * 256;
      int row = a >> 3, kq = (a & 7) * 4;
      float4 v = *reinterpret_cast<const float4*>(&A[(size_t)(m0 + row) * K + k0 + kq]);
      As[kq + 0][row] = v.x; As[kq + 1][row] = v.y;
      As[kq + 2][row] = v.z; As[kq + 3][row] = v.w;
    }
#pragma unroll
    for (int p = 0; p < 2; ++p) {
      int a = tid + p * 256;
      int kk = a >> 4, nq = (a & 15) * 4;
      *reinterpret_cast<float4*>(&Bs[kk][nq]) =
          *reinterpret_cast<const float4*>(&W[(size_t)(k0 + kk) * N + n0 + nq]);
    }
    __syncthreads();
#pragma unroll
    for (int kk = 0; kk < 32; ++kk) {
      float4 a0 = *reinterpret_cast<const float4*>(&As[kk][rg * 8]);
      float4 a1 = *reinterpret_cast<const float4*>(&As[kk][rg * 8 + 4]);
      float4 b0 = *reinterpret_cast<const float4*>(&Bs[kk][cg * 4]);
      float av[8] = {a0.x, a0.y, a0.z, a0.w, a1.x, a1.y, a1.z, a1.w};
      float bv[4] = {b0.x, b0.y, b0.z, b0.w};
#pragma unroll
      for (int i = 0; i < 8; ++i)
#pragma unroll
        for (int j = 0; j < 4; ++j)
          acc[i][j] = fmaf(av[i], bv[j], acc[i][j]);
    }
    __syncthreads();
  }

  float4 bb = *reinterpret_cast<const float4*>(&bias[n0 + cg * 4]);
  float bv[4] = {bb.x, bb.y, bb.z, bb.w};
#pragma unroll
  for (int i = 0; i < 8; ++i) {
    float vals[4];
#pragma unroll
    for (int j = 0; j < 4; ++j) {
      float v = __fadd_rn(acc[i][j], bv[j]);
      if (RELU) v = fmaxf(v, 0.f);
      vals[j] = v;
    }
    float4 o; o.x = vals[0]; o.y = vals[1]; o.z = vals[2]; o.w = vals[3];
    *reinterpret_cast<float4*>(&C[(size_t)(m0 + rg * 8 + i) * N + n0 + cg * 4]) = o;
  }
}

// ---------------------------------------------------------------------------
// Big fp32 GEMM: BM=128, BN=128, BK=16, TM=8, TN=8. (bit-exact np; encoder +
// decoder fallback)
// ---------------------------------------------------------------------------
template<bool RELU>
__global__ __launch_bounds__(256) void gemm128(
    const float* __restrict__ A, const float* __restrict__ W,
    const float* __restrict__ bias, float* __restrict__ C,
    int M, int N, int K) {
  __shared__ float As[16][132];
  __shared__ float Bs[16][132];
  const int tid  = threadIdx.x;
  const int cg   = tid & 15;
  const int rg   = tid >> 4;
  const int sw   = (cg >> 2) & 1;
  const int colA = cg * 8 + sw * 4;
  const int colB = cg * 8 + (sw ^ 1) * 4;
  const int m0   = blockIdx.x * 128;
  const int n0   = blockIdx.y * 128;

  const int arow = tid >> 2;
  const int akq  = (tid & 3) * 4;
  const int bk   = tid >> 5;
  const int bn   = (tid & 31) * 4;

  const float* Ap0 = A + (size_t)(m0 + arow) * K + akq;
  const float* Ap1 = A + (size_t)(m0 + arow + 64) * K + akq;
  const float* Wp0 = W + (size_t)bk * N + n0 + bn;
  const float* Wp1 = W + (size_t)(bk + 8) * N + n0 + bn;

  float acc[8][8];
#pragma unroll
  for (int i = 0; i < 8; ++i)
#pragma unroll
    for (int j = 0; j < 8; ++j) acc[i][j] = 0.f;

  float4 av0, av1, bv0, bv1;
  av0 = *reinterpret_cast<const float4*>(Ap0);
  av1 = *reinterpret_cast<const float4*>(Ap1);
  bv0 = *reinterpret_cast<const float4*>(Wp0);
  bv1 = *reinterpret_cast<const float4*>(Wp1);

  auto write_tile = [&]() {
    As[akq + 0][arow] = av0.x; As[akq + 1][arow] = av0.y;
    As[akq + 2][arow] = av0.z; As[akq + 3][arow] = av0.w;
    As[akq + 0][arow + 64] = av1.x; As[akq + 1][arow + 64] = av1.y;
    As[akq + 2][arow + 64] = av1.z; As[akq + 3][arow + 64] = av1.w;
    *reinterpret_cast<float4*>(&Bs[bk][bn])     = bv0;
    *reinterpret_cast<float4*>(&Bs[bk + 8][bn]) = bv1;
  };
  auto compute_tile = [&]() {
#pragma unroll
    for (int kk = 0; kk < 16; ++kk) {
      float4 a0 = *reinterpret_cast<const float4*>(&As[kk][rg * 8]);
      float4 a1 = *reinterpret_cast<const float4*>(&As[kk][rg * 8 + 4]);
      float4 b0 = *reinterpret_cast<const float4*>(&Bs[kk][colA]);
      float4 b1 = *reinterpret_cast<const float4*>(&Bs[kk][colB]);
      float rv[8] = {a0.x, a0.y, a0.z, a0.w, a1.x, a1.y, a1.z, a1.w};
      float cv[8] = {b0.x, b0.y, b0.z, b0.w, b1.x, b1.y, b1.z, b1.w};
#pragma unroll
      for (int i = 0; i < 8; ++i)
#pragma unroll
        for (int j = 0; j < 8; ++j)
          acc[i][j] = fmaf(rv[i], cv[j], acc[i][j]);
    }
  };

  write_tile();
  __syncthreads();
#pragma unroll 1
  for (int k0 = 16; k0 < K; k0 += 16) {
    av0 = *reinterpret_cast<const float4*>(Ap0 + k0);
    av1 = *reinterpret_cast<const float4*>(Ap1 + k0);
    bv0 = *reinterpret_cast<const float4*>(Wp0 + (size_t)k0 * N);
    bv1 = *reinterpret_cast<const float4*>(Wp1 + (size_t)k0 * N);
    compute_tile();
    __syncthreads();
    write_tile();
    __syncthreads();
  }
  compute_tile();

  float4 bA = *reinterpret_cast<const float4*>(&bias[n0 + colA]);
  float4 bB = *reinterpret_cast<const float4*>(&bias[n0 + colB]);
  float ba[8] = {bA.x, bA.y, bA.z, bA.w, bB.x, bB.y, bB.z, bB.w};
#pragma unroll
  for (int i = 0; i < 8; ++i) {
    size_t row = (size_t)(m0 + rg * 8 + i);
    float o[8];
#pragma unroll
    for (int j = 0; j < 8; ++j) {
      float v = __fadd_rn(acc[i][j], ba[j]);
      if (RELU) v = fmaxf(v, 0.f);
      o[j] = v;
    }
    float4 oA; oA.x = o[0]; oA.y = o[1]; oA.z = o[2]; oA.w = o[3];
    float4 oB; oB.x = o[4]; oB.y = o[5]; oB.z = o[6]; oB.w = o[7];
    *reinterpret_cast<float4*>(&C[row * N + n0 + colA]) = oA;
    *reinterpret_cast<float4*>(&C[row * N + n0 + colB]) = oB;
  }
}

// ---------------------------------------------------------------------------
// cnorm[l][k] = sum_d C[l][k][d]^2, numpy pairwise 8-acc order.
// ---------------------------------------------------------------------------
__global__ void cnorm_f32(const float* __restrict__ cb, float* __restrict__ cn) {
  int i = blockIdx.x * blockDim.x + threadIdx.x;
  if (i >= NLAYERS * NK) return;
  const float* row = cb + (size_t)i * LAT;
  float r[8];
#pragma unroll
  for (int j = 0; j < 8; ++j) r[j] = 0.f;
#pragma unroll
  for (int t = 0; t < 8; ++t)
#pragma unroll
    for (int j = 0; j < 8; ++j) {
      float v = row[t * 8 + j];
      r[j] = __fadd_rn(r[j], __fmul_rn(v, v));
    }
  cn[i] = __fadd_rn(__fadd_rn(__fadd_rn(r[0], r[1]), __fadd_rn(r[2], r[3])),
                    __fadd_rn(__fadd_rn(r[4], r[5]), __fadd_rn(r[6], r[7])));
}

// ---------------------------------------------------------------------------
// Codebook bf16 hi/lo splits, MFMA-frag-linear (proven round 3).
// ---------------------------------------------------------------------------
__global__ void split_cb(const float* __restrict__ cb,
                         unsigned short* __restrict__ cbf) {
  const int sid  = blockIdx.x * 256 + threadIdx.x;   // 0 .. 49151
  const int lane = sid & 63;
  const int grp  = sid >> 6;
  const int fg   = grp & 7;
  const int chl  = grp >> 3;
  const int nt = fg >> 2, ks = fg & 3;
  const int layer = chl >> 5, ch = chl & 31;
  const int code = ch * 64 + nt * 32 + (lane & 31);
  const int k0 = ks * 16 + (lane >> 5) * 8;
  const float* src = cb + ((size_t)layer * NK + code) * LAT + k0;
  float4 a = *(const float4*)src;
  float4 b = *(const float4*)(src + 4);
  float v[8] = {a.x, a.y, a.z, a.w, b.x, b.y, b.z, b.w};
  s16x8 hi, lo;
#pragma unroll
  for (int i = 0; i < 8; ++i) {
    unsigned short h = f2bf(v[i]);
    hi[i] = (short)h;
    lo[i] = (short)f2bf(__fsub_rn(v[i], bf2f(h)));
  }
  *(s16x8*)(cbf + ((size_t)grp * 2 + 0) * 512 + lane * 8) = hi;
  *(s16x8*)(cbf + ((size_t)grp * 2 + 1) * 512 + lane * 8) = lo;
}

// ---------------------------------------------------------------------------
// Weight bf16 hi/lo splits, frag-linear: grp = ks*(N/32)+ntg; B-frag layout
// col = lane&31, k = ks*16 + (lane>>5)*8 + i.
// ---------------------------------------------------------------------------
__global__ void split_w(const float* __restrict__ W,
                        unsigned short* __restrict__ wf, int K, int N) {
  const int total = (K / 16) * (N / 32) * 64;
  const int idx = blockIdx.x * 256 + threadIdx.x;
  if (idx >= total) return;
  const int lane = idx & 63;
  const int grp  = idx >> 6;
  const int ntn  = N / 32;
  const int ks   = grp / ntn;
  const int ntg  = grp % ntn;
  const int col  = ntg * 32 + (lane & 31);
  const int k0   = ks * 16 + (lane >> 5) * 8;
  s16x8 hi, lo;
#pragma unroll
  for (int i = 0; i < 8; ++i) {
    float v = W[(size_t)(k0 + i) * N + col];
    unsigned short h = f2bf(v);
    hi[i] = (short)h;
    lo[i] = (short)f2bf(__fsub_rn(v, bf2f(h)));
  }
  *(s16x8*)(wf + ((size_t)grp * 2 + 0) * 512 + lane * 8) = hi;
  *(s16x8*)(wf + ((size_t)grp * 2 + 1) * 512 + lane * 8) = lo;
}

// ---------------------------------------------------------------------------
// Residual quantization v2: 64 rows/block (grid = NB/64 = 1024 -> 4 blk/CU),
// 4 waves each own a code-quarter (8 chunks of 64 codes). Split-bf16 3-term
// MFMA distances + exact numpy rescue (codes provably exact).
// ---------------------------------------------------------------------------
__global__ __launch_bounds__(256, 2) void rq_mfma(
    const float* __restrict__ zg,            // [B][64] == out_res layer 0 (z)
    const float* __restrict__ cb,            // [3][2048][64] fp32
    const unsigned short* __restrict__ cbf,  // frag-linear bf16 splits
    const float* __restrict__ cnorm,         // [3][2048]
    float* __restrict__ out_codes,           // [3][B] as float
    float* __restrict__ out_quant,           // [B][64]
    float* __restrict__ out_res) {           // [3][B][64]
  __shared__ float m1S[64][4];
  __shared__ int   candS[64][16];
  __shared__ int   cntS[64][4];
  __shared__ int   flagS[64][4];
  __shared__ int   selS[64];
  __shared__ float rnS[64];
  __shared__ float bestD[256];
  __shared__ int   bestK[256];

  const int tid  = threadIdx.x;
  const int w    = tid >> 6;      // code-quarter
  const int lane = tid & 63;
  const int half = lane >> 5;
  const int lcol = lane & 31;
  const int rb0  = blockIdx.x * 64;

  s16x8 ah[2][4], al[2][4];       // residual splits, [Msub][kstep]

  for (int layer = 0; layer < NLAYERS; ++layer) {
    const float* cbL = cb + (size_t)layer * NK * LAT;
    const float* cnL = cnorm + (size_t)layer * NK;
    const unsigned short* cbfL = cbf + (size_t)layer * (NK * LAT * 2);
    float* resL = out_res + (size_t)layer * NB * LAT;

    // ---- P0: residual = z - q (np order); wave 0 writes out_res; splits ----
#pragma unroll
    for (int m = 0; m < 2; ++m) {
      const size_t row = (size_t)(rb0 + m * 32 + lcol);
#pragma unroll
      for (int ks = 0; ks < 4; ++ks) {
        const int k0 = ks * 16 + half * 8;
        const float* zp = zg + row * LAT + k0;
        float4 a = *(const float4*)zp;
        float4 b = *(const float4*)(zp + 4);
        float r[8] = {a.x, a.y, a.z, a.w, b.x, b.y, b.z, b.w};
        if (layer > 0) {
          const float* qp = out_quant + row * LAT + k0;
          float4 qa = *(const float4*)qp;
          float4 qb = *(const float4*)(qp + 4);
          float q[8] = {qa.x, qa.y, qa.z, qa.w, qb.x, qb.y, qb.z, qb.w};
#pragma unroll
          for (int i = 0; i < 8; ++i) r[i] = __fsub_rn(r[i], q[i]);
          if (w == 0) {
            float4 o0 = {r[0], r[1], r[2], r[3]};
            float4 o1 = {r[4], r[5], r[6], r[7]};
            *(float4*)(resL + row * LAT + k0) = o0;
            *(float4*)(resL + row * LAT + k0 + 4) = o1;
          }
        }
#pragma unroll
        for (int i = 0; i < 8; ++i) {
          unsigned short hh = f2bf(r[i]);
          float hf = bf2f(hh);
          ah[m][ks][i] = (short)hh;
          al[m][ks][i] = (short)f2bf(__fsub_rn(r[i], hf));
        }
      }
    }
    __syncthreads();   // resL visible

    // ---- P1: row norms (numpy pairwise 8-acc) ----
    if (tid < 64) {
      const float* rp = resL + (size_t)(rb0 + tid) * LAT;
      float r8[8] = {0.f, 0.f, 0.f, 0.f, 0.f, 0.f, 0.f, 0.f};
#pragma unroll
      for (int tb = 0; tb < 8; ++tb) {
        float4 x0 = *(const float4*)(rp + tb * 8);
        float4 x1 = *(const float4*)(rp + tb * 8 + 4);
        float v[8] = {x0.x, x0.y, x0.z, x0.w, x1.x, x1.y, x1.z, x1.w};
#pragma unroll
        for (int j = 0; j < 8; ++j)
          r8[j] = __fadd_rn(r8[j], __fmul_rn(v[j], v[j]));
      }
      rnS[tid] = __fadd_rn(
          __fadd_rn(__fadd_rn(r8[0], r8[1]), __fadd_rn(r8[2], r8[3])),
          __fadd_rn(__fadd_rn(r8[4], r8[5]), __fadd_rn(r8[6], r8[7])));
    }

    // ---- P2: MFMA distances, per-lane best-2 (5-op tracking) ----
    float v1[2][16], v2[2][16];
    int   i1[2][16];
#pragma unroll
    for (int m = 0; m < 2; ++m)
#pragma unroll
      for (int r = 0; r < 16; ++r) {
        v1[m][r] = FLT_MAX; v2[m][r] = FLT_MAX; i1[m][r] = 0;
      }

#pragma unroll 1
    for (int ch = 0; ch < 8; ++ch) {
      const int chg = w * 8 + ch;
      const unsigned short* cf = cbfL + (size_t)chg * 8192;
#pragma unroll
      for (int nt = 0; nt < 2; ++nt) {
        const int kbase = chg * 64 + nt * 32 + lcol;
        float cnv = cnL[kbase];
        s16x8 bh[4], bl[4];
#pragma unroll
        for (int ks = 0; ks < 4; ++ks) {
          bh[ks] = *(const s16x8*)(cf + ((size_t)((nt * 4 + ks) * 2 + 0) * 64 + lane) * 8);
          bl[ks] = *(const s16x8*)(cf + ((size_t)((nt * 4 + ks) * 2 + 1) * 64 + lane) * 8);
        }
        fp32x16 acc0, acc1;
#pragma unroll
        for (int r = 0; r < 16; ++r) { acc0[r] = 0.f; acc1[r] = 0.f; }
#pragma unroll
        for (int ks = 0; ks < 4; ++ks) {
          acc0 = __builtin_amdgcn_mfma_f32_32x32x16_bf16(ah[0][ks], bh[ks], acc0, 0, 0, 0);
          acc1 = __builtin_amdgcn_mfma_f32_32x32x16_bf16(ah[1][ks], bh[ks], acc1, 0, 0, 0);
          acc0 = __builtin_amdgcn_mfma_f32_32x32x16_bf16(ah[0][ks], bl[ks], acc0, 0, 0, 0);
          acc1 = __builtin_amdgcn_mfma_f32_32x32x16_bf16(ah[1][ks], bl[ks], acc1, 0, 0, 0);
          acc0 = __builtin_amdgcn_mfma_f32_32x32x16_bf16(al[0][ks], bh[ks], acc0, 0, 0, 0);
          acc1 = __builtin_amdgcn_mfma_f32_32x32x16_bf16(al[1][ks], bh[ks], acc1, 0, 0, 0);
        }
#pragma unroll
        for (int r = 0; r < 16; ++r) {
          {
            float d = fmaf(-2.f, acc0[r], cnv);
            float t = fmaxf(d, v1[0][r]);
            v2[0][r] = fminf(v2[0][r], t);
            bool c = d < v1[0][r];
            i1[0][r] = c ? kbase : i1[0][r];
            v1[0][r] = fminf(v1[0][r], d);
          }
          {
            float d = fmaf(-2.f, acc1[r], cnv);
            float t = fmaxf(d, v1[1][r]);
            v2[1][r] = fminf(v2[1][r], t);
            bool c = d < v1[1][r];
            i1[1][r] = c ? kbase : i1[1][r];
            v1[1][r] = fminf(v1[1][r], d);
          }
        }
      }
    }

    // ---- P3: per-row min across lanes/waves, candidate collection ----
#pragma unroll
    for (int m = 0; m < 2; ++m)
#pragma unroll
      for (int r = 0; r < 16; ++r) {
        float m1 = v1[m][r];
        m1 = fminf(m1, __shfl_xor(m1, 1));
        m1 = fminf(m1, __shfl_xor(m1, 2));
        m1 = fminf(m1, __shfl_xor(m1, 4));
        m1 = fminf(m1, __shfl_xor(m1, 8));
        m1 = fminf(m1, __shfl_xor(m1, 16));
        const int rowloc = m * 32 + (r & 3) + 8 * (r >> 2) + 4 * half;
        if (lcol == 0) m1S[rowloc][w] = m1;
      }
    __syncthreads();
#pragma unroll
    for (int m = 0; m < 2; ++m)
#pragma unroll
      for (int r = 0; r < 16; ++r) {
        const int rowloc = m * 32 + (r & 3) + 8 * (r >> 2) + 4 * half;
        float thr = fminf(fminf(m1S[rowloc][0], m1S[rowloc][1]),
                          fminf(m1S[rowloc][2], m1S[rowloc][3])) + DELTA;
        unsigned long long bc = __ballot(v1[m][r] <= thr);
        unsigned long long bf = __ballot(v2[m][r] <= thr);
        unsigned mc = (unsigned)(bc >> (half * 32));
        unsigned mf = (unsigned)(bf >> (half * 32));
        int pos = __popc(mc & ((1u << lcol) - 1u));
        if (v1[m][r] <= thr && pos < 4) candS[rowloc][w * 4 + pos] = i1[m][r];
        if (lcol == 0) {
          int c = __popc(mc);
          cntS[rowloc][w]  = (c < 4) ? c : 4;
          flagS[rowloc][w] = (mf != 0u) || (c > 4);
        }
      }
    __syncthreads();

    // ---- Phase A: exact np recompute for candidates (unflagged rows) ----
    if (tid < 64) {
      const int t = tid;
      if ((flagS[t][0] | flagS[t][1] | flagS[t][2] | flagS[t][3]) == 0) {
        const float* rp = resL + (size_t)(rb0 + t) * LAT;
        float rr[64];
#pragma unroll
        for (int j = 0; j < 16; ++j) {
          float4 x = *(const float4*)(rp + j * 4);
          rr[j * 4 + 0] = x.x; rr[j * 4 + 1] = x.y;
          rr[j * 4 + 2] = x.z; rr[j * 4 + 3] = x.w;
        }
        const float rn = rnS[t];
        float bd = FLT_MAX; int bk = 0x7fffffff;
#pragma unroll 1
        for (int w4 = 0; w4 < 4; ++w4) {
          const int cc = cntS[t][w4];
          for (int c = 0; c < cc; ++c) {
            int k = candS[t][w4 * 4 + c];
            const float* cp = cbL + (size_t)k * LAT;
            float dot = 0.f;
#pragma unroll
            for (int j = 0; j < 64; ++j) dot = fmaf(rr[j], cp[j], dot);
            float d = __fadd_rn(__fsub_rn(rn, __fmul_rn(2.f, dot)), cnL[k]);
            if (d < bd || (d == bd && k < bk)) { bd = d; bk = k; }
          }
        }
        selS[t] = bk;
        out_codes[(size_t)layer * NB + rb0 + t] = (float)bk;
      }
    }
    __syncthreads();

    // ---- Phase B: flagged rows -> full exact scan (rare) ----
#pragma unroll 1
    for (int t2 = 0; t2 < 64; ++t2) {
      if ((flagS[t2][0] | flagS[t2][1] | flagS[t2][2] | flagS[t2][3]) == 0) continue;
      const float* rp = resL + (size_t)(rb0 + t2) * LAT;
      const float rn = rnS[t2];
      float bd = FLT_MAX; int bk = 0x7fffffff;
#pragma unroll 1
      for (int j = 0; j < 8; ++j) {
        int k = tid * 8 + j;
        const float* cp = cbL + (size_t)k * LAT;
        float dot = 0.f;
        for (int q = 0; q < 64; ++q) dot = fmaf(rp[q], cp[q], dot);
        float d = __fadd_rn(__fsub_rn(rn, __fmul_rn(2.f, dot)), cnL[k]);
        if (d < bd || (d == bd && k < bk)) { bd = d; bk = k; }
      }
      bestD[tid] = bd; bestK[tid] = bk;
      __syncthreads();
      if (tid == 0) {
        float gd = FLT_MAX; int gk = 0x7fffffff;
        for (int i = 0; i < 256; ++i) {
          float d = bestD[i]; int k = bestK[i];
          if (d < gd || (d == gd && k < gk)) { gd = d; gk = k; }
        }
        selS[t2] = gk;
        out_codes[(size_t)layer * NB + rb0 + t2] = (float)gk;
      }
      __syncthreads();
    }

    // ---- Phase Q: quantized = C[code] + quantized (np order) ----
    if (w < 2) {
      const int m = w;
      const int rowloc = m * 32 + lcol;
      const size_t row = (size_t)(rb0 + rowloc);
      const int sel = selS[rowloc];
      const float* cp = cbL + (size_t)sel * LAT;
#pragma unroll
      for (int ks = 0; ks < 4; ++ks) {
        const int k0 = ks * 16 + half * 8;
        float4 c0 = *(const float4*)(cp + k0);
        float4 c1 = *(const float4*)(cp + k0 + 4);
        float* qp = out_quant + row * LAT + k0;
        if (layer == 0) {
          *(float4*)qp = c0; *(float4*)(qp + 4) = c1;
        } else {
          float4 q0 = *(const float4*)qp;
          float4 q1 = *(const float4*)(qp + 4);
          q0.x = __fadd_rn(c0.x, q0.x); q0.y = __fadd_rn(c0.y, q0.y);
          q0.z = __fadd_rn(c0.z, q0.z); q0.w = __fadd_rn(c0.w, q0.w);
          q1.x = __fadd_rn(c1.x, q1.x); q1.y = __fadd_rn(c1.y, q1.y);
          q1.z = __fadd_rn(c1.z, q1.z); q1.w = __fadd_rn(c1.w, q1.w);
          *(float4*)qp = q0; *(float4*)(qp + 4) = q1;
        }
      }
    }
    __syncthreads();
  }
}

// ---------------------------------------------------------------------------
// dec1: h = relu(q @ dw1 + b1), split-bf16 MFMA, output hi/lo bf16 planes.
// Block: 4 waves x 32 rows = 128 rows; BN=128 (4 ntiles); grid (NB/128, 2).
// ---------------------------------------------------------------------------
__global__ __launch_bounds__(256) void dec1_mfma(
    const float* __restrict__ q, const unsigned short* __restrict__ wf,
    const float* __restrict__ bias,
    unsigned short* __restrict__ h_hi, unsigned short* __restrict__ h_lo) {
  const int tid  = threadIdx.x;
  const int w    = tid >> 6;
  const int lane = tid & 63;
  const int half = lane >> 5;
  const int lcol = lane & 31;
  const int m0   = blockIdx.x * 128 + w * 32;
  const int n0   = blockIdx.y * 128;

  fp32x16 acc[4];
#pragma unroll
  for (int nt = 0; nt < 4; ++nt)
#pragma unroll
    for (int r = 0; r < 16; ++r) acc[nt][r] = 0.f;

  const size_t arow = (size_t)(m0 + lcol);
#pragma unroll
  for (int ks = 0; ks < 4; ++ks) {
    const float* ap = q + arow * LAT + ks * 16 + half * 8;
    float4 a0 = *(const float4*)ap;
    float4 a1 = *(const float4*)(ap + 4);
    float av[8] = {a0.x, a0.y, a0.z, a0.w, a1.x, a1.y, a1.z, a1.w};
    s16x8 ah, al;
#pragma unroll
    for (int i = 0; i < 8; ++i) {
      unsigned short hh = f2bf(av[i]);
      ah[i] = (short)hh;
      al[i] = (short)f2bf(__fsub_rn(av[i], bf2f(hh)));
    }
#pragma unroll
    for (int nt = 0; nt < 4; ++nt) {
      const int grp = ks * 8 + (blockIdx.y * 4 + nt);   // N/32 = 8
      const unsigned short* base = wf + (size_t)grp * 1024;
      s16x8 bh = *(const s16x8*)(base + lane * 8);
      s16x8 bl = *(const s16x8*)(base + 512 + lane * 8);
      acc[nt] = __builtin_amdgcn_mfma_f32_32x32x16_bf16(ah, bh, acc[nt], 0, 0, 0);
      acc[nt] = __builtin_amdgcn_mfma_f32_32x32x16_bf16(ah, bl, acc[nt], 0, 0, 0);
      acc[nt] = __builtin_amdgcn_mfma_f32_32x32x16_bf16(al, bh, acc[nt], 0, 0, 0);
    }
  }

#pragma unroll
  for (int nt = 0; nt < 4; ++nt) {
    const int col = n0 + nt * 32 + lcol;
    const float b = bias[col];
#pragma unroll
    for (int r = 0; r < 16; ++r) {
      const int rowo = (r & 3) + 8 * (r >> 2) + 4 * half;
      const size_t grow = (size_t)(m0 + rowo);
      float v = fmaxf(__fadd_rn(acc[nt][r], b), 0.f);
      unsigned short hh = f2bf(v);
      h_hi[grow * HID + col] = hh;
      h_lo[grow * HID + col] = f2bf(__fsub_rn(v, bf2f(hh)));
    }
  }
}

// ---------------------------------------------------------------------------
// dec2: x_recon = h @ dw2 + b2 (split-bf16 MFMA, h from hi/lo planes).
// Block: 4 waves x 32 rows = 128; BN=128 (4 ntiles); grid (NB/128, 4).
// ---------------------------------------------------------------------------
__global__ __launch_bounds__(256) void dec2_mfma(
    const unsigned short* __restrict__ h_hi,
    const unsigned short* __restrict__ h_lo,
    const unsigned short* __restrict__ wf,
    const float* __restrict__ bias, float* __restrict__ C) {
  const int tid  = threadIdx.x;
  const int w    = tid >> 6;
  const int lane = tid & 63;
  const int half = lane >> 5;
  const int lcol = lane & 31;
  const int m0   = blockIdx.x * 128 + w * 32;
  const int n0   = blockIdx.y * 128;

  fp32x16 acc[4];
#pragma unroll
  for (int nt = 0; nt < 4; ++nt)
#pragma unroll
    for (int r = 0; r < 16; ++r) acc[nt][r] = 0.f;

  const size_t arow = (size_t)(m0 + lcol);
#pragma unroll 1
  for (int ks = 0; ks < 16; ++ks) {
    const size_t aoff = arow * HID + ks * 16 + half * 8;
    s16x8 ah = *(const s16x8*)(h_hi + aoff);
    s16x8 al = *(const s16x8*)(h_lo + aoff);
#pragma unroll
    for (int nt = 0; nt < 4; ++nt) {
      const int grp = ks * 16 + (blockIdx.y * 4 + nt);  // N/32 = 16
      const unsigned short* base = wf + (size_t)grp * 1024;
      s16x8 bh = *(const s16x8*)(base + lane * 8);
      s16x8 bl = *(const s16x8*)(base + 512 + lane * 8);
      acc[nt] = __builtin_amdgcn_mfma_f32_32x32x16_bf16(ah, bh, acc[nt], 0, 0, 0);
      acc[nt] = __builtin_amdgcn_mfma_f32_32x32x16_bf16(ah, bl, acc[nt], 0, 0, 0);
      acc[nt] = __builtin_amdgcn_mfma_f32_32x32x16_bf16(al, bh, acc[nt], 0, 0, 0);
    }
  }

#pragma unroll
  for (int nt = 0; nt < 4; ++nt) {
    const int col = n0 + nt * 32 + lcol;
    const float b = bias[col];
#pragma unroll
    for (int r = 0; r < 16; ++r) {
      const int rowo = (r & 3) + 8 * (r >> 2) + 4 * half;
      C[(size_t)(m0 + rowo) * IN_DIM + col] = __fadd_rn(acc[nt][r], b);
    }
  }
}

// ---------------------------------------------------------------------------
extern "C" void kernel_launch(void* const* d_in, const int* in_sizes, int n_in,
                              void* d_out, int out_size, void* d_ws, size_t ws_size,
                              hipStream_t stream) {
  (void)in_sizes; (void)n_in; (void)out_size;
  const float* x   = (const float*)d_in[0];
  const float* ew1 = (const float*)d_in[1];
  const float* eb1 = (const float*)d_in[2];
  const float* ew2 = (const float*)d_in[3];
  const float* eb2 = (const float*)d_in[4];
  const float* cbk = (const float*)d_in[5];
  const float* dw1 = (const float*)d_in[6];
  const float* db1 = (const float*)d_in[7];
  const float* dw2 = (const float*)d_in[8];
  const float* db2 = (const float*)d_in[9];

  float* out     = (float*)d_out;
  float* o_codes = out;                                   // 3*B
  float* o_xrec  = out + (size_t)NLAYERS * NB;            // B*512
  float* o_quant = o_xrec + (size_t)NB * IN_DIM;          // B*64
  float* o_res   = o_quant + (size_t)NB * LAT;            // 3*B*64

  char* ws = (char*)d_ws;
  float* h            = (float*)ws;                                  // 64 MB
  unsigned short* hhi = (unsigned short*)ws;                         // 32 MB
  unsigned short* hlo = (unsigned short*)(ws + (size_t)32 * 1024 * 1024);
  float* cn           = (float*)(ws + (size_t)64 * 1024 * 1024);     // 24 KB
  unsigned short* w1f = (unsigned short*)(ws + (size_t)64 * 1024 * 1024 + 32768);
  unsigned short* w2f = (unsigned short*)(ws + (size_t)64 * 1024 * 1024 + 32768 + 65536);
  const size_t ws_need = (size_t)64 * 1024 * 1024 + 32768 + 65536 + 524288;
  const bool fast_dec = ws_size >= ws_need;

  // codebook frag splits in the dead-until-dec2 tail of o_xrec (rq-only read)
  unsigned short* cbf = (unsigned short*)(o_xrec + (size_t)16 * 1024 * 1024);

  cnorm_f32<<<(NLAYERS * NK + 255) / 256, 256, 0, stream>>>(cbk, cn);
  split_cb<<<192, 256, 0, stream>>>(cbk, cbf);
  if (fast_dec) {
    split_w<<<((LAT / 16) * (HID / 32) * 64 + 255) / 256, 256, 0, stream>>>(dw1, w1f, LAT, HID);
    split_w<<<((HID / 16) * (IN_DIM / 32) * 64 + 255) / 256, 256, 0, stream>>>(dw2, w2f, HID, IN_DIM);
  }
  // encoder (bit-exact fp32; z -> codes chain must be exact)
  gemm128<true ><<<dim3(NB / 128, HID / 128), 256, 0, stream>>>(x, ew1, eb1, h,     NB, HID, IN_DIM);
  gemm_f32<false><<<dim3(NB / 128, LAT / 64),  256, 0, stream>>>(h, ew2, eb2, o_res, NB, LAT, HID);
  // residual quantization (MFMA approx + exact rescue; codes exact)
  rq_mfma<<<NB / 64, 256, 0, stream>>>(o_res, cbk, cbf, cn, o_codes, o_quant, o_res);
  // decoder
  if (fast_dec) {
    dec1_mfma<<<dim3(NB / 128, 2), 256, 0, stream>>>(o_quant, w1f, db1, hhi, hlo);
    dec2_mfma<<<dim3(NB / 128, 4), 256, 0, stream>>>(hhi, hlo, w2f, db2, o_xrec);
  } else {
    gemm128<true ><<<dim3(NB / 128, HID / 128),    256, 0, stream>>>(o_quant, dw1, db1, h,      NB, HID,    LAT);
    gemm128<false><<<dim3(NB / 128, IN_DIM / 128), 256, 0, stream>>>(h,       dw2, db2, o_xrec, NB, IN_DIM, HID);
  }
}

// Round 5
// 694.095 us; speedup vs baseline: 1.9129x; 1.1530x over previous
//
#include <hip/hip_runtime.h>
#include <float.h>

#define NB      65536
#define IN_DIM  512
#define HID     256
#define LAT     64
#define NLAYERS 3
#define NK      2048
#define DELTA   1e-2f

typedef __attribute__((ext_vector_type(8)))  short s16x8;   // 8 bf16 (4 VGPR)
typedef __attribute__((ext_vector_type(16))) float fp32x16; // MFMA 32x32 acc

__device__ __forceinline__ unsigned short f2bf(float v) {  // fp32 -> bf16 RNE
  unsigned u = __float_as_uint(v);
  unsigned r = (u + 0x7fffu + ((u >> 16) & 1u)) >> 16;
  return (unsigned short)r;
}
__device__ __forceinline__ float bf2f(unsigned short h) {
  return __uint_as_float((unsigned)h << 16);
}

// ---------------------------------------------------------------------------
// enc2-style GEMM (N=64): BM=128, BN=64, BK=32, TM=8, TN=4. (bit-exact np)
// ---------------------------------------------------------------------------
template<bool RELU>
__global__ __launch_bounds__(256) void gemm_f32(
    const float* __restrict__ A, const float* __restrict__ W,
    const float* __restrict__ bias, float* __restrict__ C,
    int M, int N, int K) {
  __shared__ float As[32][132];
  __shared__ float Bs[32][64];
  const int tid = threadIdx.x;
  const int cg  = tid & 15;
  const int rg  = tid >> 4;
  const int m0  = blockIdx.x * 128;
  const int n0  = blockIdx.y * 64;

  float acc[8][4];
#pragma unroll
  for (int i = 0; i < 8; ++i)
#pragma unroll
    for (int j = 0; j < 4; ++j) acc[i][j] = 0.f;

  for (int k0 = 0; k0 < K; k0 += 32) {
#pragma unroll
    for (int p = 0; p < 4; ++p) {
      int a = tid + p * 256;
      int row = a >> 3, kq = (a & 7) * 4;
      float4 v = *reinterpret_cast<const float4*>(&A[(size_t)(m0 + row) * K + k0 + kq]);
      As[kq + 0][row] = v.x; As[kq + 1][row] = v.y;
      As[kq + 2][row] = v.z; As[kq + 3][row] = v.w;
    }
#pragma unroll
    for (int p = 0; p < 2; ++p) {
      int a = tid + p * 256;
      int kk = a >> 4, nq = (a & 15) * 4;
      *reinterpret_cast<float4*>(&Bs[kk][nq]) =
          *reinterpret_cast<const float4*>(&W[(size_t)(k0 + kk) * N + n0 + nq]);
    }
    __syncthreads();
#pragma unroll
    for (int kk = 0; kk < 32; ++kk) {
      float4 a0 = *reinterpret_cast<const float4*>(&As[kk][rg * 8]);
      float4 a1 = *reinterpret_cast<const float4*>(&As[kk][rg * 8 + 4]);
      float4 b0 = *reinterpret_cast<const float4*>(&Bs[kk][cg * 4]);
      float av[8] = {a0.x, a0.y, a0.z, a0.w, a1.x, a1.y, a1.z, a1.w};
      float bv[4] = {b0.x, b0.y, b0.z, b0.w};
#pragma unroll
      for (int i = 0; i < 8; ++i)
#pragma unroll
        for (int j = 0; j < 4; ++j)
          acc[i][j] = fmaf(av[i], bv[j], acc[i][j]);
    }
    __syncthreads();
  }

  float4 bb = *reinterpret_cast<const float4*>(&bias[n0 + cg * 4]);
  float bv[4] = {bb.x, bb.y, bb.z, bb.w};
#pragma unroll
  for (int i = 0; i < 8; ++i) {
    float vals[4];
#pragma unroll
    for (int j = 0; j < 4; ++j) {
      float v = __fadd_rn(acc[i][j], bv[j]);
      if (RELU) v = fmaxf(v, 0.f);
      vals[j] = v;
    }
    float4 o; o.x = vals[0]; o.y = vals[1]; o.z = vals[2]; o.w = vals[3];
    *reinterpret_cast<float4*>(&C[(size_t)(m0 + rg * 8 + i) * N + n0 + cg * 4]) = o;
  }
}

// ---------------------------------------------------------------------------
// Big fp32 GEMM: BM=128, BN=128, BK=16, TM=8, TN=8. (bit-exact np; encoder)
// ---------------------------------------------------------------------------
template<bool RELU>
__global__ __launch_bounds__(256) void gemm128(
    const float* __restrict__ A, const float* __restrict__ W,
    const float* __restrict__ bias, float* __restrict__ C,
    int M, int N, int K) {
  __shared__ float As[16][132];
  __shared__ float Bs[16][132];
  const int tid  = threadIdx.x;
  const int cg   = tid & 15;
  const int rg   = tid >> 4;
  const int sw   = (cg >> 2) & 1;
  const int colA = cg * 8 + sw * 4;
  const int colB = cg * 8 + (sw ^ 1) * 4;
  const int m0   = blockIdx.x * 128;
  const int n0   = blockIdx.y * 128;

  const int arow = tid >> 2;
  const int akq  = (tid & 3) * 4;
  const int bk   = tid >> 5;
  const int bn   = (tid & 31) * 4;

  const float* Ap0 = A + (size_t)(m0 + arow) * K + akq;
  const float* Ap1 = A + (size_t)(m0 + arow + 64) * K + akq;
  const float* Wp0 = W + (size_t)bk * N + n0 + bn;
  const float* Wp1 = W + (size_t)(bk + 8) * N + n0 + bn;

  float acc[8][8];
#pragma unroll
  for (int i = 0; i < 8; ++i)
#pragma unroll
    for (int j = 0; j < 8; ++j) acc[i][j] = 0.f;

  float4 av0, av1, bv0, bv1;
  av0 = *reinterpret_cast<const float4*>(Ap0);
  av1 = *reinterpret_cast<const float4*>(Ap1);
  bv0 = *reinterpret_cast<const float4*>(Wp0);
  bv1 = *reinterpret_cast<const float4*>(Wp1);

  auto write_tile = [&]() {
    As[akq + 0][arow] = av0.x; As[akq + 1][arow] = av0.y;
    As[akq + 2][arow] = av0.z; As[akq + 3][arow] = av0.w;
    As[akq + 0][arow + 64] = av1.x; As[akq + 1][arow + 64] = av1.y;
    As[akq + 2][arow + 64] = av1.z; As[akq + 3][arow + 64] = av1.w;
    *reinterpret_cast<float4*>(&Bs[bk][bn])     = bv0;
    *reinterpret_cast<float4*>(&Bs[bk + 8][bn]) = bv1;
  };
  auto compute_tile = [&]() {
#pragma unroll
    for (int kk = 0; kk < 16; ++kk) {
      float4 a0 = *reinterpret_cast<const float4*>(&As[kk][rg * 8]);
      float4 a1 = *reinterpret_cast<const float4*>(&As[kk][rg * 8 + 4]);
      float4 b0 = *reinterpret_cast<const float4*>(&Bs[kk][colA]);
      float4 b1 = *reinterpret_cast<const float4*>(&Bs[kk][colB]);
      float rv[8] = {a0.x, a0.y, a0.z, a0.w, a1.x, a1.y, a1.z, a1.w};
      float cv[8] = {b0.x, b0.y, b0.z, b0.w, b1.x, b1.y, b1.z, b1.w};
#pragma unroll
      for (int i = 0; i < 8; ++i)
#pragma unroll
        for (int j = 0; j < 8; ++j)
          acc[i][j] = fmaf(rv[i], cv[j], acc[i][j]);
    }
  };

  write_tile();
  __syncthreads();
#pragma unroll 1
  for (int k0 = 16; k0 < K; k0 += 16) {
    av0 = *reinterpret_cast<const float4*>(Ap0 + k0);
    av1 = *reinterpret_cast<const float4*>(Ap1 + k0);
    bv0 = *reinterpret_cast<const float4*>(Wp0 + (size_t)k0 * N);
    bv1 = *reinterpret_cast<const float4*>(Wp1 + (size_t)k0 * N);
    compute_tile();
    __syncthreads();
    write_tile();
    __syncthreads();
  }
  compute_tile();

  float4 bA = *reinterpret_cast<const float4*>(&bias[n0 + colA]);
  float4 bB = *reinterpret_cast<const float4*>(&bias[n0 + colB]);
  float ba[8] = {bA.x, bA.y, bA.z, bA.w, bB.x, bB.y, bB.z, bB.w};
#pragma unroll
  for (int i = 0; i < 8; ++i) {
    size_t row = (size_t)(m0 + rg * 8 + i);
    float o[8];
#pragma unroll
    for (int j = 0; j < 8; ++j) {
      float v = __fadd_rn(acc[i][j], ba[j]);
      if (RELU) v = fmaxf(v, 0.f);
      o[j] = v;
    }
    float4 oA; oA.x = o[0]; oA.y = o[1]; oA.z = o[2]; oA.w = o[3];
    float4 oB; oB.x = o[4]; oB.y = o[5]; oB.z = o[6]; oB.w = o[7];
    *reinterpret_cast<float4*>(&C[row * N + n0 + colA]) = oA;
    *reinterpret_cast<float4*>(&C[row * N + n0 + colB]) = oB;
  }
}

// ---------------------------------------------------------------------------
// cnorm[l][k] = sum_d C[l][k][d]^2, numpy pairwise 8-acc order.
// ---------------------------------------------------------------------------
__global__ void cnorm_f32(const float* __restrict__ cb, float* __restrict__ cn) {
  int i = blockIdx.x * blockDim.x + threadIdx.x;
  if (i >= NLAYERS * NK) return;
  const float* row = cb + (size_t)i * LAT;
  float r[8];
#pragma unroll
  for (int j = 0; j < 8; ++j) r[j] = 0.f;
#pragma unroll
  for (int t = 0; t < 8; ++t)
#pragma unroll
    for (int j = 0; j < 8; ++j) {
      float v = row[t * 8 + j];
      r[j] = __fadd_rn(r[j], __fmul_rn(v, v));
    }
  cn[i] = __fadd_rn(__fadd_rn(__fadd_rn(r[0], r[1]), __fadd_rn(r[2], r[3])),
                    __fadd_rn(__fadd_rn(r[4], r[5]), __fadd_rn(r[6], r[7])));
}

// ---------------------------------------------------------------------------
// Codebook bf16 hi/lo splits, MFMA-frag-linear (proven round 3).
// Per chunk chg (64 codes): 16 KB contiguous, (nt,ks,hl,lane,i) order.
// ---------------------------------------------------------------------------
__global__ void split_cb(const float* __restrict__ cb,
                         unsigned short* __restrict__ cbf) {
  const int sid  = blockIdx.x * 256 + threadIdx.x;   // 0 .. 49151
  const int lane = sid & 63;
  const int grp  = sid >> 6;
  const int fg   = grp & 7;
  const int chl  = grp >> 3;
  const int nt = fg >> 2, ks = fg & 3;
  const int layer = chl >> 5, ch = chl & 31;
  const int code = ch * 64 + nt * 32 + (lane & 31);
  const int k0 = ks * 16 + (lane >> 5) * 8;
  const float* src = cb + ((size_t)layer * NK + code) * LAT + k0;
  float4 a = *(const float4*)src;
  float4 b = *(const float4*)(src + 4);
  float v[8] = {a.x, a.y, a.z, a.w, b.x, b.y, b.z, b.w};
  s16x8 hi, lo;
#pragma unroll
  for (int i = 0; i < 8; ++i) {
    unsigned short h = f2bf(v[i]);
    hi[i] = (short)h;
    lo[i] = (short)f2bf(__fsub_rn(v[i], bf2f(h)));
  }
  *(s16x8*)(cbf + ((size_t)grp * 2 + 0) * 512 + lane * 8) = hi;
  *(s16x8*)(cbf + ((size_t)grp * 2 + 1) * 512 + lane * 8) = lo;
}

// ---------------------------------------------------------------------------
// Weight bf16 hi/lo splits, frag-linear (decoder).
// ---------------------------------------------------------------------------
__global__ void split_w(const float* __restrict__ W,
                        unsigned short* __restrict__ wf, int K, int N) {
  const int total = (K / 16) * (N / 32) * 64;
  const int idx = blockIdx.x * 256 + threadIdx.x;
  if (idx >= total) return;
  const int lane = idx & 63;
  const int grp  = idx >> 6;
  const int ntn  = N / 32;
  const int ks   = grp / ntn;
  const int ntg  = grp % ntn;
  const int col  = ntg * 32 + (lane & 31);
  const int k0   = ks * 16 + (lane >> 5) * 8;
  s16x8 hi, lo;
#pragma unroll
  for (int i = 0; i < 8; ++i) {
    float v = W[(size_t)(k0 + i) * N + col];
    unsigned short h = f2bf(v);
    hi[i] = (short)h;
    lo[i] = (short)f2bf(__fsub_rn(v, bf2f(h)));
  }
  *(s16x8*)(wf + ((size_t)grp * 2 + 0) * 512 + lane * 8) = hi;
  *(s16x8*)(wf + ((size_t)grp * 2 + 1) * 512 + lane * 8) = lo;
}

// ---------------------------------------------------------------------------
// Residual quantization v3: 128 rows/block (grid 512 = 2 blk/CU), 4 waves =
// (rgrp x nthalf). Codebook chunk (64 codes, 16 KB hi+lo frags) staged in LDS,
// double-buffered with T14 split (issue loads early, ds_write late). cnorm
// staged per layer. Split-bf16 3-term MFMA + exact numpy rescue (codes exact).
// ---------------------------------------------------------------------------
__global__ __launch_bounds__(256, 2) void rq_mfma(
    const float* __restrict__ zg,            // [B][64] == out_res layer 0 (z)
    const float* __restrict__ cb,            // [3][2048][64] fp32
    const unsigned short* __restrict__ cbf,  // frag-linear bf16 splits
    const float* __restrict__ cnorm,         // [3][2048]
    float* __restrict__ out_codes,           // [3][B] as float
    float* __restrict__ out_quant,           // [B][64]
    float* __restrict__ out_res) {           // [3][B][64]
  __shared__ unsigned short cbS[2][8192];    // 2 x 16 KB chunk frags
  __shared__ float cnSL[NK];                 // 8 KB layer cnorm
  __shared__ float m1S[128][2];
  __shared__ int   candS[128][8];
  __shared__ int   cntS[128][2];
  __shared__ int   flagS[128][2];
  __shared__ int   selS[128];
  __shared__ float rnS[128];
  __shared__ float bestD[256];
  __shared__ int   bestK[256];

  const int tid    = threadIdx.x;
  const int w      = tid >> 6;
  const int rgrp   = w >> 1;      // row group: rows rgrp*64 ..
  const int nthalf = w & 1;       // nt-tile half of each chunk
  const int lane   = tid & 63;
  const int half   = lane >> 5;
  const int lcol   = lane & 31;
  const int rb0    = blockIdx.x * 128;

  s16x8 ah[2][4], al[2][4];       // residual splits, [Msub][kstep]

  for (int layer = 0; layer < NLAYERS; ++layer) {
    const float* cbL = cb + (size_t)layer * NK * LAT;
    const float* cnL = cnorm + (size_t)layer * NK;
    const unsigned short* cbfL = cbf + (size_t)layer * (NK * LAT * 2);
    float* resL = out_res + (size_t)layer * NB * LAT;

    // ---- P0: residual = z - q (np order); nthalf==0 waves write resL ----
#pragma unroll
    for (int m = 0; m < 2; ++m) {
      const size_t row = (size_t)(rb0 + rgrp * 64 + m * 32 + lcol);
#pragma unroll
      for (int ks = 0; ks < 4; ++ks) {
        const int k0 = ks * 16 + half * 8;
        const float* zp = zg + row * LAT + k0;
        float4 a = *(const float4*)zp;
        float4 b = *(const float4*)(zp + 4);
        float r[8] = {a.x, a.y, a.z, a.w, b.x, b.y, b.z, b.w};
        if (layer > 0) {
          const float* qp = out_quant + row * LAT + k0;
          float4 qa = *(const float4*)qp;
          float4 qb = *(const float4*)(qp + 4);
          float q[8] = {qa.x, qa.y, qa.z, qa.w, qb.x, qb.y, qb.z, qb.w};
#pragma unroll
          for (int i = 0; i < 8; ++i) r[i] = __fsub_rn(r[i], q[i]);
          if (nthalf == 0) {
            float4 o0 = {r[0], r[1], r[2], r[3]};
            float4 o1 = {r[4], r[5], r[6], r[7]};
            *(float4*)(resL + row * LAT + k0) = o0;
            *(float4*)(resL + row * LAT + k0 + 4) = o1;
          }
        }
#pragma unroll
        for (int i = 0; i < 8; ++i) {
          unsigned short hh = f2bf(r[i]);
          float hf = bf2f(hh);
          ah[m][ks][i] = (short)hh;
          al[m][ks][i] = (short)f2bf(__fsub_rn(r[i], hf));
        }
      }
    }

    // ---- issue chunk-0 + cnorm loads (T14 early) ----
    s16x8 stg[4];
#pragma unroll
    for (int p = 0; p < 4; ++p)
      stg[p] = *(const s16x8*)(cbfL + p * 2048 + tid * 8);
    float4 cn0 = *(const float4*)(cnL + tid * 8);
    float4 cn1 = *(const float4*)(cnL + tid * 8 + 4);
    __syncthreads();   // resL writes visible (layer>0)

    // ---- write staged chunk-0 + cnorm; P1 row norms ----
#pragma unroll
    for (int p = 0; p < 4; ++p)
      *(s16x8*)(&cbS[0][p * 2048 + tid * 8]) = stg[p];
    *(float4*)(&cnSL[tid * 8])     = cn0;
    *(float4*)(&cnSL[tid * 8 + 4]) = cn1;
    if (tid < 128) {
      const float* rp = resL + (size_t)(rb0 + tid) * LAT;
      float r8[8] = {0.f, 0.f, 0.f, 0.f, 0.f, 0.f, 0.f, 0.f};
#pragma unroll
      for (int tb = 0; tb < 8; ++tb) {
        float4 x0 = *(const float4*)(rp + tb * 8);
        float4 x1 = *(const float4*)(rp + tb * 8 + 4);
        float v[8] = {x0.x, x0.y, x0.z, x0.w, x1.x, x1.y, x1.z, x1.w};
#pragma unroll
        for (int j = 0; j < 8; ++j)
          r8[j] = __fadd_rn(r8[j], __fmul_rn(v[j], v[j]));
      }
      rnS[tid] = __fadd_rn(
          __fadd_rn(__fadd_rn(r8[0], r8[1]), __fadd_rn(r8[2], r8[3])),
          __fadd_rn(__fadd_rn(r8[4], r8[5]), __fadd_rn(r8[6], r8[7])));
    }
    __syncthreads();

    // ---- P2: chunk loop, LDS double-buffered ----
    float v1[2][16], v2[2][16];
    int   i1[2][16];
#pragma unroll
    for (int m = 0; m < 2; ++m)
#pragma unroll
      for (int r = 0; r < 16; ++r) {
        v1[m][r] = FLT_MAX; v2[m][r] = FLT_MAX; i1[m][r] = 0;
      }

#pragma unroll 1
    for (int ch = 0; ch < 32; ++ch) {
      const int buf = ch & 1;
      // T14: issue next-chunk global loads now
      const bool haveNext = (ch + 1) < 32;
      if (haveNext) {
        const unsigned short* src = cbfL + (size_t)(ch + 1) * 8192;
#pragma unroll
        for (int p = 0; p < 4; ++p)
          stg[p] = *(const s16x8*)(src + p * 2048 + tid * 8);
      }

      // B frags for my nt-half from LDS
      s16x8 bh[4], bl[4];
#pragma unroll
      for (int ks = 0; ks < 4; ++ks) {
        bh[ks] = *(const s16x8*)(&cbS[buf][((nthalf * 4 + ks) * 2 + 0) * 512 + lane * 8]);
        bl[ks] = *(const s16x8*)(&cbS[buf][((nthalf * 4 + ks) * 2 + 1) * 512 + lane * 8]);
      }
      const int kbase = ch * 64 + nthalf * 32 + lcol;
      const float cnv = cnSL[kbase];

      fp32x16 acc0, acc1;
#pragma unroll
      for (int r = 0; r < 16; ++r) { acc0[r] = 0.f; acc1[r] = 0.f; }
#pragma unroll
      for (int ks = 0; ks < 4; ++ks) {
        acc0 = __builtin_amdgcn_mfma_f32_32x32x16_bf16(ah[0][ks], bh[ks], acc0, 0, 0, 0);
        acc1 = __builtin_amdgcn_mfma_f32_32x32x16_bf16(ah[1][ks], bh[ks], acc1, 0, 0, 0);
        acc0 = __builtin_amdgcn_mfma_f32_32x32x16_bf16(ah[0][ks], bl[ks], acc0, 0, 0, 0);
        acc1 = __builtin_amdgcn_mfma_f32_32x32x16_bf16(ah[1][ks], bl[ks], acc1, 0, 0, 0);
        acc0 = __builtin_amdgcn_mfma_f32_32x32x16_bf16(al[0][ks], bh[ks], acc0, 0, 0, 0);
        acc1 = __builtin_amdgcn_mfma_f32_32x32x16_bf16(al[1][ks], bh[ks], acc1, 0, 0, 0);
      }

      // best-2 tracking (min/max pair fuses to v_med3_f32)
#pragma unroll
      for (int r = 0; r < 16; ++r) {
        {
          float d = fmaf(-2.f, acc0[r], cnv);
          float nv2 = fminf(fmaxf(d, v1[0][r]), v2[0][r]);
          bool c = d < v1[0][r];
          i1[0][r] = c ? kbase : i1[0][r];
          v1[0][r] = fminf(v1[0][r], d);
          v2[0][r] = nv2;
        }
        {
          float d = fmaf(-2.f, acc1[r], cnv);
          float nv2 = fminf(fmaxf(d, v1[1][r]), v2[1][r]);
          bool c = d < v1[1][r];
          i1[1][r] = c ? kbase : i1[1][r];
          v1[1][r] = fminf(v1[1][r], d);
          v2[1][r] = nv2;
        }
      }

      // T14 late: write staged next chunk, then publish
      if (haveNext) {
#pragma unroll
        for (int p = 0; p < 4; ++p)
          *(s16x8*)(&cbS[buf ^ 1][p * 2048 + tid * 8]) = stg[p];
      }
      __syncthreads();
    }

    // ---- P3: per-row min across lanes + both nt-half waves; candidates ----
#pragma unroll
    for (int m = 0; m < 2; ++m)
#pragma unroll
      for (int r = 0; r < 16; ++r) {
        float m1 = v1[m][r];
        m1 = fminf(m1, __shfl_xor(m1, 1));
        m1 = fminf(m1, __shfl_xor(m1, 2));
        m1 = fminf(m1, __shfl_xor(m1, 4));
        m1 = fminf(m1, __shfl_xor(m1, 8));
        m1 = fminf(m1, __shfl_xor(m1, 16));
        const int rowloc = rgrp * 64 + m * 32 + (r & 3) + 8 * (r >> 2) + 4 * half;
        if (lcol == 0) m1S[rowloc][nthalf] = m1;
      }
    __syncthreads();
#pragma unroll
    for (int m = 0; m < 2; ++m)
#pragma unroll
      for (int r = 0; r < 16; ++r) {
        const int rowloc = rgrp * 64 + m * 32 + (r & 3) + 8 * (r >> 2) + 4 * half;
        float thr = fminf(m1S[rowloc][0], m1S[rowloc][1]) + DELTA;
        unsigned long long bc = __ballot(v1[m][r] <= thr);
        unsigned long long bf = __ballot(v2[m][r] <= thr);
        unsigned mc = (unsigned)(bc >> (half * 32));
        unsigned mf = (unsigned)(bf >> (half * 32));
        int pos = __popc(mc & ((1u << lcol) - 1u));
        if (v1[m][r] <= thr && pos < 4) candS[rowloc][nthalf * 4 + pos] = i1[m][r];
        if (lcol == 0) {
          int c = __popc(mc);
          cntS[rowloc][nthalf]  = (c < 4) ? c : 4;
          flagS[rowloc][nthalf] = (mf != 0u) || (c > 4);
        }
      }
    __syncthreads();

    // ---- Phase A: exact np recompute for candidates (unflagged rows) ----
    if (tid < 128) {
      const int t = tid;
      if ((flagS[t][0] | flagS[t][1]) == 0) {
        const float* rp = resL + (size_t)(rb0 + t) * LAT;
        float rr[64];
#pragma unroll
        for (int j = 0; j < 16; ++j) {
          float4 x = *(const float4*)(rp + j * 4);
          rr[j * 4 + 0] = x.x; rr[j * 4 + 1] = x.y;
          rr[j * 4 + 2] = x.z; rr[j * 4 + 3] = x.w;
        }
        const float rn = rnS[t];
        float bd = FLT_MAX; int bk = 0x7fffffff;
        const int c0 = cntS[t][0], c1n = cntS[t][1];
        for (int c = 0; c < c0 + c1n; ++c) {
          int k = candS[t][(c < c0) ? c : (4 + c - c0)];
          const float* cp = cbL + (size_t)k * LAT;
          float dot = 0.f;
#pragma unroll
          for (int j = 0; j < 64; ++j) dot = fmaf(rr[j], cp[j], dot);
          float d = __fadd_rn(__fsub_rn(rn, __fmul_rn(2.f, dot)), cnL[k]);
          if (d < bd || (d == bd && k < bk)) { bd = d; bk = k; }
        }
        selS[t] = bk;
        out_codes[(size_t)layer * NB + rb0 + t] = (float)bk;
      }
    }
    __syncthreads();

    // ---- Phase B: flagged rows -> full exact scan (rare) ----
#pragma unroll 1
    for (int t2 = 0; t2 < 128; ++t2) {
      if ((flagS[t2][0] | flagS[t2][1]) == 0) continue;
      const float* rp = resL + (size_t)(rb0 + t2) * LAT;
      const float rn = rnS[t2];
      float bd = FLT_MAX; int bk = 0x7fffffff;
#pragma unroll 1
      for (int j = 0; j < 8; ++j) {
        int k = tid * 8 + j;
        const float* cp = cbL + (size_t)k * LAT;
        float dot = 0.f;
        for (int q = 0; q < 64; ++q) dot = fmaf(rp[q], cp[q], dot);
        float d = __fadd_rn(__fsub_rn(rn, __fmul_rn(2.f, dot)), cnL[k]);
        if (d < bd || (d == bd && k < bk)) { bd = d; bk = k; }
      }
      bestD[tid] = bd; bestK[tid] = bk;
      __syncthreads();
      if (tid == 0) {
        float gd = FLT_MAX; int gk = 0x7fffffff;
        for (int i = 0; i < 256; ++i) {
          float d = bestD[i]; int k = bestK[i];
          if (d < gd || (d == gd && k < gk)) { gd = d; gk = k; }
        }
        selS[t2] = gk;
        out_codes[(size_t)layer * NB + rb0 + t2] = (float)gk;
      }
      __syncthreads();
    }

    // ---- Phase Q: quantized = C[code] + quantized (np order) ----
    if (nthalf == 0) {
#pragma unroll
      for (int m = 0; m < 2; ++m) {
        const int rowloc = rgrp * 64 + m * 32 + lcol;
        const size_t row = (size_t)(rb0 + rowloc);
        const int sel = selS[rowloc];
        const float* cp = cbL + (size_t)sel * LAT;
#pragma unroll
        for (int ks = 0; ks < 4; ++ks) {
          const int k0 = ks * 16 + half * 8;
          float4 c0 = *(const float4*)(cp + k0);
          float4 c1 = *(const float4*)(cp + k0 + 4);
          float* qp = out_quant + row * LAT + k0;
          if (layer == 0) {
            *(float4*)qp = c0; *(float4*)(qp + 4) = c1;
          } else {
            float4 q0 = *(const float4*)qp;
            float4 q1 = *(const float4*)(qp + 4);
            q0.x = __fadd_rn(c0.x, q0.x); q0.y = __fadd_rn(c0.y, q0.y);
            q0.z = __fadd_rn(c0.z, q0.z); q0.w = __fadd_rn(c0.w, q0.w);
            q1.x = __fadd_rn(c1.x, q1.x); q1.y = __fadd_rn(c1.y, q1.y);
            q1.z = __fadd_rn(c1.z, q1.z); q1.w = __fadd_rn(c1.w, q1.w);
            *(float4*)qp = q0; *(float4*)(qp + 4) = q1;
          }
        }
      }
    }
    __syncthreads();
  }
}

// ---------------------------------------------------------------------------
// dec1: h = relu(q @ dw1 + b1), split-bf16 MFMA, output hi/lo bf16 planes.
// ---------------------------------------------------------------------------
__global__ __launch_bounds__(256) void dec1_mfma(
    const float* __restrict__ q, const unsigned short* __restrict__ wf,
    const float* __restrict__ bias,
    unsigned short* __restrict__ h_hi, unsigned short* __restrict__ h_lo) {
  const int tid  = threadIdx.x;
  const int w    = tid >> 6;
  const int lane = tid & 63;
  const int half = lane >> 5;
  const int lcol = lane & 31;
  const int m0   = blockIdx.x * 128 + w * 32;
  const int n0   = blockIdx.y * 128;

  fp32x16 acc[4];
#pragma unroll
  for (int nt = 0; nt < 4; ++nt)
#pragma unroll
    for (int r = 0; r < 16; ++r) acc[nt][r] = 0.f;

  const size_t arow = (size_t)(m0 + lcol);
#pragma unroll
  for (int ks = 0; ks < 4; ++ks) {
    const float* ap = q + arow * LAT + ks * 16 + half * 8;
    float4 a0 = *(const float4*)ap;
    float4 a1 = *(const float4*)(ap + 4);
    float av[8] = {a0.x, a0.y, a0.z, a0.w, a1.x, a1.y, a1.z, a1.w};
    s16x8 ah, al;
#pragma unroll
    for (int i = 0; i < 8; ++i) {
      unsigned short hh = f2bf(av[i]);
      ah[i] = (short)hh;
      al[i] = (short)f2bf(__fsub_rn(av[i], bf2f(hh)));
    }
#pragma unroll
    for (int nt = 0; nt < 4; ++nt) {
      const int grp = ks * 8 + (blockIdx.y * 4 + nt);   // N/32 = 8
      const unsigned short* base = wf + (size_t)grp * 1024;
      s16x8 bh = *(const s16x8*)(base + lane * 8);
      s16x8 bl = *(const s16x8*)(base + 512 + lane * 8);
      acc[nt] = __builtin_amdgcn_mfma_f32_32x32x16_bf16(ah, bh, acc[nt], 0, 0, 0);
      acc[nt] = __builtin_amdgcn_mfma_f32_32x32x16_bf16(ah, bl, acc[nt], 0, 0, 0);
      acc[nt] = __builtin_amdgcn_mfma_f32_32x32x16_bf16(al, bh, acc[nt], 0, 0, 0);
    }
  }

#pragma unroll
  for (int nt = 0; nt < 4; ++nt) {
    const int col = n0 + nt * 32 + lcol;
    const float b = bias[col];
#pragma unroll
    for (int r = 0; r < 16; ++r) {
      const int rowo = (r & 3) + 8 * (r >> 2) + 4 * half;
      const size_t grow = (size_t)(m0 + rowo);
      float v = fmaxf(__fadd_rn(acc[nt][r], b), 0.f);
      unsigned short hh = f2bf(v);
      h_hi[grow * HID + col] = hh;
      h_lo[grow * HID + col] = f2bf(__fsub_rn(v, bf2f(hh)));
    }
  }
}

// ---------------------------------------------------------------------------
// dec2: x_recon = h @ dw2 + b2 (split-bf16 MFMA, h from hi/lo planes).
// ---------------------------------------------------------------------------
__global__ __launch_bounds__(256) void dec2_mfma(
    const unsigned short* __restrict__ h_hi,
    const unsigned short* __restrict__ h_lo,
    const unsigned short* __restrict__ wf,
    const float* __restrict__ bias, float* __restrict__ C) {
  const int tid  = threadIdx.x;
  const int w    = tid >> 6;
  const int lane = tid & 63;
  const int half = lane >> 5;
  const int lcol = lane & 31;
  const int m0   = blockIdx.x * 128 + w * 32;
  const int n0   = blockIdx.y * 128;

  fp32x16 acc[4];
#pragma unroll
  for (int nt = 0; nt < 4; ++nt)
#pragma unroll
    for (int r = 0; r < 16; ++r) acc[nt][r] = 0.f;

  const size_t arow = (size_t)(m0 + lcol);
#pragma unroll 1
  for (int ks = 0; ks < 16; ++ks) {
    const size_t aoff = arow * HID + ks * 16 + half * 8;
    s16x8 ah = *(const s16x8*)(h_hi + aoff);
    s16x8 al = *(const s16x8*)(h_lo + aoff);
#pragma unroll
    for (int nt = 0; nt < 4; ++nt) {
      const int grp = ks * 16 + (blockIdx.y * 4 + nt);  // N/32 = 16
      const unsigned short* base = wf + (size_t)grp * 1024;
      s16x8 bh = *(const s16x8*)(base + lane * 8);
      s16x8 bl = *(const s16x8*)(base + 512 + lane * 8);
      acc[nt] = __builtin_amdgcn_mfma_f32_32x32x16_bf16(ah, bh, acc[nt], 0, 0, 0);
      acc[nt] = __builtin_amdgcn_mfma_f32_32x32x16_bf16(ah, bl, acc[nt], 0, 0, 0);
      acc[nt] = __builtin_amdgcn_mfma_f32_32x32x16_bf16(al, bh, acc[nt], 0, 0, 0);
    }
  }

#pragma unroll
  for (int nt = 0; nt < 4; ++nt) {
    const int col = n0 + nt * 32 + lcol;
    const float b = bias[col];
#pragma unroll
    for (int r = 0; r < 16; ++r) {
      const int rowo = (r & 3) + 8 * (r >> 2) + 4 * half;
      C[(size_t)(m0 + rowo) * IN_DIM + col] = __fadd_rn(acc[nt][r], b);
    }
  }
}

// ---------------------------------------------------------------------------
extern "C" void kernel_launch(void* const* d_in, const int* in_sizes, int n_in,
                              void* d_out, int out_size, void* d_ws, size_t ws_size,
                              hipStream_t stream) {
  (void)in_sizes; (void)n_in; (void)out_size;
  const float* x   = (const float*)d_in[0];
  const float* ew1 = (const float*)d_in[1];
  const float* eb1 = (const float*)d_in[2];
  const float* ew2 = (const float*)d_in[3];
  const float* eb2 = (const float*)d_in[4];
  const float* cbk = (const float*)d_in[5];
  const float* dw1 = (const float*)d_in[6];
  const float* db1 = (const float*)d_in[7];
  const float* dw2 = (const float*)d_in[8];
  const float* db2 = (const float*)d_in[9];

  float* out     = (float*)d_out;
  float* o_codes = out;                                   // 3*B
  float* o_xrec  = out + (size_t)NLAYERS * NB;            // B*512
  float* o_quant = o_xrec + (size_t)NB * IN_DIM;          // B*64
  float* o_res   = o_quant + (size_t)NB * LAT;            // 3*B*64

  char* ws = (char*)d_ws;
  float* h            = (float*)ws;                                  // 64 MB
  unsigned short* hhi = (unsigned short*)ws;                         // 32 MB
  unsigned short* hlo = (unsigned short*)(ws + (size_t)32 * 1024 * 1024);
  float* cn           = (float*)(ws + (size_t)64 * 1024 * 1024);     // 24 KB
  unsigned short* w1f = (unsigned short*)(ws + (size_t)64 * 1024 * 1024 + 32768);
  unsigned short* w2f = (unsigned short*)(ws + (size_t)64 * 1024 * 1024 + 32768 + 65536);
  const size_t ws_need = (size_t)64 * 1024 * 1024 + 32768 + 65536 + 524288;
  const bool fast_dec = ws_size >= ws_need;

  // codebook frag splits in the dead-until-dec2 tail of o_xrec (rq-only read)
  unsigned short* cbf = (unsigned short*)(o_xrec + (size_t)16 * 1024 * 1024);

  cnorm_f32<<<(NLAYERS * NK + 255) / 256, 256, 0, stream>>>(cbk, cn);
  split_cb<<<192, 256, 0, stream>>>(cbk, cbf);
  if (fast_dec) {
    split_w<<<((LAT / 16) * (HID / 32) * 64 + 255) / 256, 256, 0, stream>>>(dw1, w1f, LAT, HID);
    split_w<<<((HID / 16) * (IN_DIM / 32) * 64 + 255) / 256, 256, 0, stream>>>(dw2, w2f, HID, IN_DIM);
  }
  // encoder (bit-exact fp32; z -> codes chain must be exact)
  gemm128<true ><<<dim3(NB / 128, HID / 128), 256, 0, stream>>>(x, ew1, eb1, h,     NB, HID, IN_DIM);
  gemm_f32<false><<<dim3(NB / 128, LAT / 64),  256, 0, stream>>>(h, ew2, eb2, o_res, NB, LAT, HID);
  // residual quantization (LDS-staged MFMA approx + exact rescue; codes exact)
  rq_mfma<<<NB / 128, 256, 0, stream>>>(o_res, cbk, cbf, cn, o_codes, o_quant, o_res);
  // decoder
  if (fast_dec) {
    dec1_mfma<<<dim3(NB / 128, 2), 256, 0, stream>>>(o_quant, w1f, db1, hhi, hlo);
    dec2_mfma<<<dim3(NB / 128, 4), 256, 0, stream>>>(hhi, hlo, w2f, db2, o_xrec);
  } else {
    gemm128<true ><<<dim3(NB / 128, HID / 128),    256, 0, stream>>>(o_quant, dw1, db1, h,      NB, HID,    LAT);
    gemm128<false><<<dim3(NB / 128, IN_DIM / 128), 256, 0, stream>>>(h,       dw2, db2, o_xrec, NB, IN_DIM, HID);
  }
}